// Round 4
// baseline (399.141 us; speedup 1.0000x reference)
//
#include <hip/hip_runtime.h>
#include <hip/hip_fp16.h>
#include <stdint.h>

// GCN forward. N=100000, E=3000000, G=256, F_IN=64, NHID=32.
// R1: 96M global scatter-atomics = L2 atomic ceiling (312us) -> gather.
// R2: naive CSR build = 16x write amplification (random sub-line stores,
//     8 incoherent L2s, write-allocate thrash).
// R3/R7/R8: 8-slice XCD build = clean writes but 8x edge re-read (FETCH 107MB).
// R5: LDS atomics ~3.6cyc/op; few-address LDS atomics serialize (R12 radix).
// R6: small hot global atomic arrays = 32B line ping-pong per op.
// R9: nontemporal_store is write-through (~56B per random sub-line store).
// R11: slicing ewc scatter: clean writes but 8x mask re-read cost more.
// R12: radix mask inversion lost to double mask read + 8-address LDS atomic
//     serialization. Reverted to R10 plain byte stores.
// R13: kC SINGLE PASS via XCD-grouped chunk remap: chunk=(blk&7)*64+(blk>>3)
//     csrB positions monotone in chunk -> contiguous per-XCD sub-runs.
// R14 FAILED: packed 2-bit atomicOr. Atomic RMW = same ~32B/op sector cost,
//     plus issue throttle. LESSON: random fine-grain scatter ~32-40B HBM/op.
// R15: default cls=2 via memset; scatter only km/um (2M stores). 119->78MB,
//     kA1 65->54us. CONFIRMED per-store cost model.
// R16: (resubmit — previous bench was an infra failure, no counters)
//  a) kA1 XCD-PINNED scatter: ewc (3MB) fits ONE XCD's 4MB L2. All scatter
//     blocks at blockIdx%8==0 (XCD0 per R13's verified mapping); histogram
//     chunks on idx%8!=0 (XCDs 1-7). Mask reads via nontemporal_load so
//     streaming doesn't evict ewc. Stores coalesce in-L2 (~42 stores/line);
//     HBM write = 3MB clean writeback at kernel end.
//  b) kD reads csrB ONCE: stage segment into LDS raw[] during count pass,
//     counting-sort scatter reads LDS (saves 12MB HBM re-read).

#define BLK 256
#define NCHUNK 512          // edge chunks for count/scatter
#define AGRID 586           // kA1 grid: 74 scatter (idx%8==0) + 512 histogram
#define MAXNB 1600          // max buckets (N<=102400)
#define ENTCAP 2560         // per-bucket LDS entries (lambda=1920, 14 sigma)

// kA1: fused. Blocks idx%8!=0 (512 of them): per-chunk node-bucket histogram.
// Blocks idx%8==0 (74, all XCD0): class scatter km->0, um->1 into ewc
// (pre-memset to 2). ewc stays resident in XCD0's L2 -> stores coalesce.
__global__ void kA1(const int* __restrict__ col, int* __restrict__ cnt,
                    int n_edges, int NB,
                    const int* __restrict__ km, const int* __restrict__ um,
                    int s0, int s1,
                    uint8_t* __restrict__ ewc) {
    int t = threadIdx.x;
    int idx = blockIdx.x;
    if ((idx & 7) != 0) {
        __shared__ int lh[MAXNB];
        int c = idx - (idx >> 3) - 1;          // [0, NCHUNK)
        for (int b = t; b < NB; b += BLK) lh[b] = 0;
        __syncthreads();
        int chunk = (n_edges + NCHUNK - 1) / NCHUNK;
        int e0 = c * chunk, e1 = min(e0 + chunk, n_edges);
        for (int e = e0 + t; e < e1; e += BLK) atomicAdd(&lh[col[e] >> 6], 1);
        __syncthreads();
        for (int b = t; b < NB; b += BLK) cnt[(size_t)c * NB + b] = lh[b];
    } else {
        const int NSB = (AGRID + 7) / 8;       // 74 scatter blocks
        int ord = idx >> 3;                    // [0, 74)
        int total = s0 + s1;
        for (int i = ord * BLK + t; i < total; i += NSB * BLK) {
            int e; uint8_t cls;
            if (i < s0) { e = __builtin_nontemporal_load(&km[i]);      cls = 0; }
            else        { e = __builtin_nontemporal_load(&um[i - s0]); cls = 1; }
            ewc[e] = cls;
        }
    }
}

// kB2: 16 node-buckets per block. Tile cnt through LDS with coalesced 64B
// reads, scan over chunks, write offTT TRANSPOSED for sequential kC reads.
__global__ void kB2(const int* __restrict__ cnt, int* __restrict__ offTT,
                    int* __restrict__ tot, int NB) {
    __shared__ int tile[NCHUNK * 16];     // 32KB
    __shared__ int segs[16][17];
    int t = threadIdx.x;
    int b0 = blockIdx.x * 16;
    for (int idx = t; idx < NCHUNK * 16; idx += BLK) {
        int c = idx >> 4, b = idx & 15;
        tile[idx] = (b0 + b < NB) ? cnt[(size_t)c * NB + b0 + b] : 0;
    }
    __syncthreads();
    int b = t & 15, seg = t >> 4;         // 16 segs x 16 buckets
    int psum = 0;
#pragma unroll
    for (int k = 0; k < 32; ++k) psum += tile[(seg * 32 + k) * 16 + b];
    segs[seg][b] = psum;
    __syncthreads();
    int ex = 0;
    for (int ss = 0; ss < seg; ++ss) ex += segs[ss][b];
    int run = ex;
#pragma unroll
    for (int k = 0; k < 32; ++k) {
        int c = seg * 32 + k;
        if (b0 + b < NB) offTT[(size_t)c * NB + b0 + b] = run;
        run += tile[c * 16 + b];
    }
    if (seg == 15 && b0 + b < NB) tot[b0 + b] = run;
}

// kBase3: fused. Blocks 0..7: fold emb through gcn (Wfull, hWbias).
// Block 8: exclusive scan of tot[NB] -> base_[0..NB].
__global__ void kBase3(const int* __restrict__ tot, int* __restrict__ base_, int NB,
                       const float* __restrict__ emb_W, const float* __restrict__ emb_b,
                       const float* __restrict__ gcn_W,
                       float* __restrict__ Wfull, float* __restrict__ hWbias) {
    int t = threadIdx.x;
    if (blockIdx.x < 8) {
        int k = blockIdx.x * 8 + (t >> 5), j = t & 31;
        float acc;
        if (k == 0) {
            acc = gcn_W[j];
        } else {
            int m = k - 1;
            acc = 0.0f;
#pragma unroll 9
            for (int tt = 0; tt < 63; ++tt)
                acc += emb_W[m * 63 + tt] * gcn_W[(1 + tt) * 32 + j];
        }
        Wfull[k * 32 + j] = acc;
        if (blockIdx.x == 0 && t < 32) {
            float bacc = 0.0f;
            for (int tt = 0; tt < 63; ++tt)
                bacc += emb_b[tt] * gcn_W[(1 + tt) * 32 + t];
            hWbias[t] = bacc;
        }
    } else {
        __shared__ int s[BLK];
        const int K = 7;  // 256*7 = 1792 >= MAXNB
        int v[K]; int sum = 0;
#pragma unroll
        for (int k = 0; k < K; ++k) {
            int i = t * K + k;
            v[k] = (i < NB) ? tot[i] : 0;
            sum += v[k];
        }
        s[t] = sum; __syncthreads();
        for (int st = 1; st < BLK; st <<= 1) {
            int x = (t >= st) ? s[t - st] : 0;
            __syncthreads(); s[t] += x; __syncthreads();
        }
        int ex = (t == 0) ? 0 : s[t - 1];
#pragma unroll
        for (int k = 0; k < K; ++k) {
            int i = t * K + k;
            if (i < NB) base_[i] = ex;
            ex += v[k];
        }
        if (t == BLK - 1) base_[NB] = s[BLK - 1];
    }
}

// kC: SINGLE-PASS scatter with XCD-grouped chunk remap.
// chunk = (blockIdx&7)*(NCHUNK/8) + (blockIdx>>3): XCD k processes chunks
// [k*64,(k+1)*64) -> each bucket's csrB segment is written as 8 contiguous
// per-XCD sub-runs (monotone offsets in chunk) -> no cross-XCD line sharing
// except sub-run boundaries. Edges read ONCE. All-bucket LDS cursors.
// Entry = (local_col<<19)|(row<<2)|cls.
__global__ void kC_scatter(const int* __restrict__ row, const int* __restrict__ col,
                           const uint8_t* __restrict__ ewc, const int* __restrict__ base_,
                           const int* __restrict__ offTT, int* __restrict__ csrB,
                           int n_edges, int NB) {
    __shared__ int cur[MAXNB];
    int t = threadIdx.x;
    int c = (blockIdx.x & 7) * (NCHUNK / 8) + (blockIdx.x >> 3);
    const int* offrow = offTT + (size_t)c * NB;
    for (int b = t; b < NB; b += BLK) cur[b] = base_[b] + offrow[b];
    __syncthreads();
    int chunk = (n_edges + NCHUNK - 1) / NCHUNK;
    int e0 = c * chunk, e1 = min(e0 + chunk, n_edges);
    for (int e = e0 + t; e < e1; e += BLK) {
        int cc = col[e];
        int pos = atomicAdd(&cur[cc >> 6], 1);
        csrB[pos] = ((cc & 63) << 19) | (row[e] << 2) | (ewc[e] & 3);
    }
}

// k4f: fused degree + GEMM per 64-node bucket.
__global__ void k4f_gemm(const float* __restrict__ x, const float* __restrict__ Wfull,
                         const float* __restrict__ hWbias, const int* __restrict__ base_,
                         const int* __restrict__ csrB, const float* __restrict__ mw,
                         __half* __restrict__ hWs, int n_nodes) {
    __shared__ float Wl[64 * 32];      // 8KB
    __shared__ float xs[64 * 64];      // 16KB
    __shared__ int ct4[256];           // 1KB
    __shared__ float dv[64];
    int b = blockIdx.x, t = threadIdx.x;
    for (int idx = t; idx < 2048; idx += BLK) Wl[idx] = Wfull[idx];
    if (t < 256) ct4[t] = 0;
    int rowBase = b * 64;
    for (int idx = t; idx < 4096; idx += BLK) {
        int r = rowBase + (idx >> 6);
        xs[idx] = (r < n_nodes) ? x[(size_t)r * 64 + (idx & 63)] : 0.0f;
    }
    __syncthreads();
    int p0 = base_[b], p1 = base_[b + 1];
    for (int p = p0 + t; p < p1; p += BLK) {
        int e = csrB[p];
        atomicAdd(&ct4[((e >> 19) << 2) | (e & 3)], 1);
    }
    __syncthreads();
    if (t < 64) {
        float a = mw[0], bb = mw[1], c3 = mw[2];
        float m = fmaxf(a, fmaxf(bb, c3));
        float ea = __expf(a - m), eb = __expf(bb - m), ec = __expf(c3 - m);
        float inv = 1.0f / (ea + eb + ec);
        float deg = (ea * inv) * (float)ct4[t * 4]
                  + (eb * inv) * (float)ct4[t * 4 + 1]
                  + (ec * inv) * (float)ct4[t * 4 + 2]
                  + (float)ct4[t * 4 + 3]
                  + 1.0f;
        dv[t] = rsqrtf(deg);
    }
    __syncthreads();
    int j = t & 31, lr = t >> 5;
#pragma unroll
    for (int k8 = 0; k8 < 8; ++k8) {
        int r = lr + 8 * k8;
        int n = rowBase + r;
        if (n < n_nodes) {
            float acc = hWbias[j];
#pragma unroll
            for (int k = 0; k < 64; ++k)
                acc += xs[r * 64 + k] * Wl[k * 32 + j];
            hWs[(size_t)n * 32 + j] = __float2half(dv[r] * acc);
        }
    }
}

// kD: per-bucket consumer. Stage csrB segment in LDS (read once), count,
// counting-sort from LDS, per-node register gather (16 lanes/node, half2),
// relu, run-length pool.
__global__ void kD_gather(const int* __restrict__ base_, const int* __restrict__ csrB,
                          const __half2* __restrict__ hws2,
                          const float* __restrict__ mw, const float* __restrict__ gcn_b,
                          const int* __restrict__ batch, float* __restrict__ pooled,
                          int n_nodes) {
    __shared__ int ent[ENTCAP];
    __shared__ int raw[ENTCAP];       // staged csrB segment (csrB read ONCE)
    __shared__ float res[64 * 33];
    __shared__ int ct4[256];
    __shared__ int ct[64], st[64], cur[64];
    __shared__ float dl[64], gb[32];
    __shared__ int bl[64];
    int b = blockIdx.x, t = threadIdx.x;
    if (t < 256) ct4[t] = 0;
    if (t < 64) {
        int n = b * 64 + t;
        bl[t] = (n < n_nodes) ? batch[n] : -1;
    }
    if (t < 32) gb[t] = gcn_b[t];
    __syncthreads();
    int p0 = base_[b], p1 = base_[b + 1];
    int m = min(p1 - p0, ENTCAP);     // clamp (14 sigma margin, never hit)
    for (int i = t; i < m; i += BLK) {
        int e = csrB[p0 + i];
        raw[i] = e;
        atomicAdd(&ct4[((e >> 19) << 2) | (e & 3)], 1);
    }
    __syncthreads();
    float a = mw[0], bb = mw[1], c3 = mw[2];
    float mx = fmaxf(a, fmaxf(bb, c3));
    float ea = __expf(a - mx), eb = __expf(bb - mx), ec = __expf(c3 - mx);
    float inv = 1.0f / (ea + eb + ec);
    float w0 = ea * inv, w1 = eb * inv, w2 = ec * inv;
    if (t < 64) {
        int c0 = ct4[t * 4], c1 = ct4[t * 4 + 1], c2 = ct4[t * 4 + 2], c33 = ct4[t * 4 + 3];
        ct[t] = c0 + c1 + c2 + c33;
        dl[t] = rsqrtf(w0 * (float)c0 + w1 * (float)c1 + w2 * (float)c2
                       + (float)c33 + 1.0f);
    }
    __syncthreads();
    if (t < 64) st[t] = ct[t];
    __syncthreads();
    for (int off = 1; off < 64; off <<= 1) {
        int v = (t < 64 && t >= off) ? st[t - off] : 0;
        __syncthreads();
        if (t < 64) st[t] += v;
        __syncthreads();
    }
    if (t < 64) { st[t] -= ct[t]; cur[t] = st[t]; }
    __syncthreads();
    for (int i = t; i < m; i += BLK) {
        int e = raw[i];
        int pos = atomicAdd(&cur[e >> 19], 1);
        ent[pos] = e;
    }
    __syncthreads();
    int grp = t >> 4, j2 = t & 15;
#pragma unroll
    for (int idx = 0; idx < 4; ++idx) {
        int lc = grp + 16 * idx;
        int n = b * 64 + lc;
        float rx = 0.0f, ry = 0.0f;
        if (n < n_nodes) {
            int s = st[lc], end = s + ct[lc];
            float ax = 0.0f, ay = 0.0f;
            int p = s;
            for (; p + 8 <= end; p += 8) {
                int e0 = ent[p],     e1 = ent[p + 1], e2 = ent[p + 2], e3 = ent[p + 3];
                int e4 = ent[p + 4], e5 = ent[p + 5], e6 = ent[p + 6], e7 = ent[p + 7];
                __half2 h0 = hws2[(size_t)((e0 >> 2) & 0x1FFFF) * 16 + j2];
                __half2 h1 = hws2[(size_t)((e1 >> 2) & 0x1FFFF) * 16 + j2];
                __half2 h2 = hws2[(size_t)((e2 >> 2) & 0x1FFFF) * 16 + j2];
                __half2 h3 = hws2[(size_t)((e3 >> 2) & 0x1FFFF) * 16 + j2];
                __half2 h4 = hws2[(size_t)((e4 >> 2) & 0x1FFFF) * 16 + j2];
                __half2 h5 = hws2[(size_t)((e5 >> 2) & 0x1FFFF) * 16 + j2];
                __half2 h6 = hws2[(size_t)((e6 >> 2) & 0x1FFFF) * 16 + j2];
                __half2 h7 = hws2[(size_t)((e7 >> 2) & 0x1FFFF) * 16 + j2];
                float f0 = ((e0 & 3) == 0) ? w0 : (((e0 & 3) == 1) ? w1 : w2);
                float f1 = ((e1 & 3) == 0) ? w0 : (((e1 & 3) == 1) ? w1 : w2);
                float f2 = ((e2 & 3) == 0) ? w0 : (((e2 & 3) == 1) ? w1 : w2);
                float f3 = ((e3 & 3) == 0) ? w0 : (((e3 & 3) == 1) ? w1 : w2);
                float f4 = ((e4 & 3) == 0) ? w0 : (((e4 & 3) == 1) ? w1 : w2);
                float f5 = ((e5 & 3) == 0) ? w0 : (((e5 & 3) == 1) ? w1 : w2);
                float f6 = ((e6 & 3) == 0) ? w0 : (((e6 & 3) == 1) ? w1 : w2);
                float f7 = ((e7 & 3) == 0) ? w0 : (((e7 & 3) == 1) ? w1 : w2);
                float2 g0 = __half22float2(h0), g1 = __half22float2(h1);
                float2 g2 = __half22float2(h2), g3 = __half22float2(h3);
                float2 g4 = __half22float2(h4), g5 = __half22float2(h5);
                float2 g6 = __half22float2(h6), g7 = __half22float2(h7);
                ax += f0 * g0.x + f1 * g1.x + f2 * g2.x + f3 * g3.x
                    + f4 * g4.x + f5 * g5.x + f6 * g6.x + f7 * g7.x;
                ay += f0 * g0.y + f1 * g1.y + f2 * g2.y + f3 * g3.y
                    + f4 * g4.y + f5 * g5.y + f6 * g6.y + f7 * g7.y;
            }
            for (; p < end; ++p) {
                int e0 = ent[p];
                __half2 h0 = hws2[(size_t)((e0 >> 2) & 0x1FFFF) * 16 + j2];
                float f0 = ((e0 & 3) == 0) ? w0 : (((e0 & 3) == 1) ? w1 : w2);
                float2 g0 = __half22float2(h0);
                ax += f0 * g0.x; ay += f0 * g0.y;
            }
            float2 self = __half22float2(hws2[(size_t)n * 16 + j2]);
            float di = dl[lc];
            rx = fmaxf(di * (ax + self.x) + gb[2 * j2], 0.0f);
            ry = fmaxf(di * (ay + self.y) + gb[2 * j2 + 1], 0.0f);
        }
        res[lc * 33 + 2 * j2]     = rx;
        res[lc * 33 + 2 * j2 + 1] = ry;
    }
    __syncthreads();
    if (t < 32) {
        int j = t;
        float sum = 0.0f; int g0 = bl[0];
        for (int lc = 0; lc < 64; ++lc) {
            if (bl[lc] < 0) break;
            float val = res[lc * 33 + j];
            if (bl[lc] != g0) { atomicAdd(&pooled[g0 * 32 + j], sum); sum = 0.0f; g0 = bl[lc]; }
            sum += val;
        }
        if (g0 >= 0) atomicAdd(&pooled[g0 * 32 + j], sum);
    }
}

// k7: head: z = relu(pooled @ fc1_W + fc1_b); out = z @ out_W + out_b
__global__ void k7_head(const float* __restrict__ pooled, const float* __restrict__ fc1_W,
                        const float* __restrict__ fc1_b, const float* __restrict__ out_W,
                        const float* __restrict__ out_b, float* __restrict__ out,
                        int n_graphs) {
    __shared__ float Wl[32 * 32];
    __shared__ float bl[32];
    __shared__ float owl[32];
    int t = threadIdx.x;
    for (int idx = t; idx < 1024; idx += BLK) Wl[idx] = fc1_W[idx];
    if (t < 32) { bl[t] = fc1_b[t]; owl[t] = out_W[t]; }
    __syncthreads();
    if (t < n_graphs) {
        float p[32];
#pragma unroll
        for (int k = 0; k < 32; ++k) p[k] = pooled[t * 32 + k];
        float acc = 0.0f;
        for (int j = 0; j < 32; ++j) {
            float z = bl[j];
#pragma unroll
            for (int k = 0; k < 32; ++k) z += p[k] * Wl[k * 32 + j];
            z = fmaxf(z, 0.0f);
            acc += z * owl[j];
        }
        out[t] = acc + out_b[0];
    }
}

static inline size_t align_up(size_t v, size_t a) { return (v + a - 1) & ~(a - 1); }

extern "C" void kernel_launch(void* const* d_in, const int* in_sizes, int n_in,
                              void* d_out, int out_size, void* d_ws, size_t ws_size,
                              hipStream_t stream) {
    const float* x     = (const float*)d_in[0];
    const int*   ei    = (const int*)d_in[1];
    const int*   batch = (const int*)d_in[2];
    const int*   km    = (const int*)d_in[3];
    const int*   um    = (const int*)d_in[4];
    const int*   om    = (const int*)d_in[5];
    const float* mw    = (const float*)d_in[6];
    const float* emb_W = (const float*)d_in[7];
    const float* emb_b = (const float*)d_in[8];
    const float* gcn_W = (const float*)d_in[9];
    const float* gcn_b = (const float*)d_in[10];
    const float* fc1_W = (const float*)d_in[11];
    const float* fc1_b = (const float*)d_in[12];
    const float* out_W = (const float*)d_in[13];
    const float* out_b = (const float*)d_in[14];
    (void)om;

    const int n_nodes  = in_sizes[0] / 64;
    const int n_edges  = in_sizes[1] / 2;
    const int s0 = in_sizes[3], s1 = in_sizes[4];
    const int n_graphs = out_size;  // 256

    const int* row = ei;
    const int* col = ei + n_edges;

    const int NB  = (n_nodes + 63) >> 6;   // 1563 buckets of 64 nodes
    const int NGB = (NB + 15) / 16;        // kB2 blocks

    // ---- workspace layout (~28.3 MB) ----
    char* base = (char*)d_ws;
    float*   pooled = (float*)base;   base += (size_t)n_graphs * 32 * 4;   // zeroed
    int*     cnt    = (int*)base;     base += (size_t)NCHUNK * NB * 4;     // 3.2 MB
    int*     offTT  = (int*)base;     base += (size_t)NCHUNK * NB * 4;     // 3.2 MB
    int*     tot    = (int*)base;     base += (size_t)NB * 4;
    int*     base_  = (int*)base;     base += (size_t)(NB + 1) * 4;
    float*   Wfull  = (float*)base;   base += 2048 * 4;
    float*   hWbias = (float*)base;   base += 32 * 4;
    uint8_t* ewc    = (uint8_t*)base; base += align_up((size_t)n_edges, 64);
    int*     csrB   = (int*)base;     base += (size_t)n_edges * 4;         // 12 MB
    base = (char*)align_up((size_t)base, 64);
    __half*  hWs    = (__half*)base;  base += (size_t)n_nodes * 32 * 2;    // 6.4 MB

    hipMemsetAsync(pooled, 0, (size_t)n_graphs * 32 * 4, stream);
    hipMemsetAsync(ewc, 2, align_up((size_t)n_edges, 64), stream);  // default cls=2 (obs)

    kA1<<<AGRID, BLK, 0, stream>>>(col, cnt, n_edges, NB, km, um, s0, s1, ewc);
    kB2<<<NGB, BLK, 0, stream>>>(cnt, offTT, tot, NB);
    kBase3<<<9, BLK, 0, stream>>>(tot, base_, NB, emb_W, emb_b, gcn_W, Wfull, hWbias);
    kC_scatter<<<NCHUNK, BLK, 0, stream>>>(row, col, ewc, base_, offTT, csrB,
                                           n_edges, NB);
    k4f_gemm<<<NB, BLK, 0, stream>>>(x, Wfull, hWbias, base_, csrB, mw, hWs, n_nodes);
    kD_gather<<<NB, BLK, 0, stream>>>(base_, csrB, (const __half2*)hWs, mw,
                                      gcn_b, batch, pooled, n_nodes);
    k7_head<<<1, BLK, 0, stream>>>(pooled, fc1_W, fc1_b, out_W, out_b, (float*)d_out, n_graphs);
}

// Round 5
// 314.088 us; speedup vs baseline: 1.2708x; 1.2708x over previous
//
#include <hip/hip_runtime.h>
#include <hip/hip_fp16.h>
#include <stdint.h>

// GCN forward. N=100000, E=3000000, G=256, F_IN=64, NHID=32.
// R1: 96M global scatter-atomics = L2 atomic ceiling (312us) -> gather.
// R2: naive CSR build = 16x write amplification (random sub-line stores).
// R5: LDS atomics ~3.6cyc/op; few-address LDS atomics serialize (R12 radix).
// R6: small hot global atomic arrays = 32B line ping-pong per op.
// R9: nontemporal_store is write-through (~56B per random sub-line store).
// R13: kC SINGLE PASS via XCD-grouped contiguous chunk ranges: per-bucket
//     csrB positions monotone in chunk -> ~960B per-XCD sub-runs, CLEAN.
// R14 FAILED: packed 2-bit atomicOr. Atomic RMW = same ~32B/op sector cost
//     + issue throttle. LESSON: random scatter ~32-40B HBM/op, store OR atomic.
// R15: default cls=2 via memset; scatter only km/um (2M stores). 119->78MB,
//     kA1 65->54us. CONFIRMED per-store cost model.
// R16 FAILED: XCD-pinned ewc scatter. WRITE_SIZE UNCHANGED (80MB) and
//     1/8-machine serialization -> kA1 141us. LESSON: dirty random sub-line
//     stores do NOT accumulate in L2 even when target fits one XCD's L2.
//     The 32-40B/store law is unconditional for line-shared random targets.
//     Clean scatter REQUIRES: each line written by ONE block, densely.
// R17 (this round): eliminate ewc. Power-of-2 chunks (8192). kA1 class
//     blocks bucket mask entries into kl[bucket][block][96] uint16 cells
//     (192B, line-aligned, single-writer -> clean per R13's pattern).
//     kC stages chunk classes into LDS clsL[8192] and looks up locally.
//     kl unions with hWs (dead before k4f). kD keeps csrB-once staging.

#define BLK 256
#define NCHUNK 512          // chunk slots (power-of-2 CHK each)
#define CHKSH 13
#define CHK 8192            // edges per chunk; used chunks = ceil(E/8192)=367
#define NCB 128             // class-bucketing writer blocks
#define CELLCAP 96          // entries per (bucket,block) cell; lambda~43, 8sig
#define MAXNB 1600          // max node buckets (N<=102400)
#define ENTCAP 2560         // per-bucket LDS entries (lambda=1920, 14 sigma)

// kA1: fused. Blocks [0,NCHUNK): per-chunk node-bucket histogram (LDS).
// Blocks [NCHUNK, NCHUNK+NCB): class bucketing. Block b scans a contiguous
// slice of km|um, deposits (local_e<<1|cls) uint16 into its PRIVATE cells
// kl[bucket][b][0..96). Cells are 192B line-aligned, single-writer ->
// writes coalesce in L2 (working set 512 cells ~96KB/block). cnt2[b][bucket]
// records fill counts (clean 2KB row write per block).
__global__ void kA1(const int* __restrict__ col, int* __restrict__ cnt,
                    int n_edges, int NB,
                    const int* __restrict__ km, const int* __restrict__ um,
                    int s0, int s1,
                    uint16_t* __restrict__ kl, int* __restrict__ cnt2) {
    int t = threadIdx.x;
    if (blockIdx.x < NCHUNK) {
        __shared__ int lh[MAXNB];
        int c = blockIdx.x;
        for (int b = t; b < NB; b += BLK) lh[b] = 0;
        __syncthreads();
        int e0 = c << CHKSH, e1 = min(e0 + CHK, n_edges);
        for (int e = e0 + t; e < e1; e += BLK) atomicAdd(&lh[col[e] >> 6], 1);
        __syncthreads();
        for (int b = t; b < NB; b += BLK) cnt[(size_t)c * NB + b] = lh[b];
    } else {
        __shared__ int cur2[NCHUNK];
        int b = blockIdx.x - NCHUNK;          // [0, NCB)
        for (int i = t; i < NCHUNK; i += BLK) cur2[i] = 0;
        __syncthreads();
        int total = s0 + s1;
        int slice = (total + NCB - 1) / NCB;
        int i0 = b * slice, i1 = min(i0 + slice, total);
        for (int i = i0 + t; i < i1; i += BLK) {
            int e, cls;
            if (i < s0) { e = km[i];      cls = 0; }
            else        { e = um[i - s0]; cls = 1; }
            int bu = e >> CHKSH;
            int pos = atomicAdd(&cur2[bu], 1);
            if (pos < CELLCAP)
                kl[((size_t)bu * NCB + b) * CELLCAP + pos] =
                    (uint16_t)(((e & (CHK - 1)) << 1) | cls);
        }
        __syncthreads();
        for (int i = t; i < NCHUNK; i += BLK) cnt2[(size_t)b * NCHUNK + i] = cur2[i];
    }
}

// kB2: 16 node-buckets per block. Tile cnt through LDS with coalesced 64B
// reads, scan over chunks, write offTT TRANSPOSED for sequential kC reads.
__global__ void kB2(const int* __restrict__ cnt, int* __restrict__ offTT,
                    int* __restrict__ tot, int NB) {
    __shared__ int tile[NCHUNK * 16];     // 32KB
    __shared__ int segs[16][17];
    int t = threadIdx.x;
    int b0 = blockIdx.x * 16;
    for (int idx = t; idx < NCHUNK * 16; idx += BLK) {
        int c = idx >> 4, b = idx & 15;
        tile[idx] = (b0 + b < NB) ? cnt[(size_t)c * NB + b0 + b] : 0;
    }
    __syncthreads();
    int b = t & 15, seg = t >> 4;         // 16 segs x 16 buckets
    int psum = 0;
#pragma unroll
    for (int k = 0; k < 32; ++k) psum += tile[(seg * 32 + k) * 16 + b];
    segs[seg][b] = psum;
    __syncthreads();
    int ex = 0;
    for (int ss = 0; ss < seg; ++ss) ex += segs[ss][b];
    int run = ex;
#pragma unroll
    for (int k = 0; k < 32; ++k) {
        int c = seg * 32 + k;
        if (b0 + b < NB) offTT[(size_t)c * NB + b0 + b] = run;
        run += tile[c * 16 + b];
    }
    if (seg == 15 && b0 + b < NB) tot[b0 + b] = run;
}

// kBase3: fused. Blocks 0..7: fold emb through gcn (Wfull, hWbias).
// Block 8: exclusive scan of tot[NB] -> base_[0..NB].
__global__ void kBase3(const int* __restrict__ tot, int* __restrict__ base_, int NB,
                       const float* __restrict__ emb_W, const float* __restrict__ emb_b,
                       const float* __restrict__ gcn_W,
                       float* __restrict__ Wfull, float* __restrict__ hWbias) {
    int t = threadIdx.x;
    if (blockIdx.x < 8) {
        int k = blockIdx.x * 8 + (t >> 5), j = t & 31;
        float acc;
        if (k == 0) {
            acc = gcn_W[j];
        } else {
            int m = k - 1;
            acc = 0.0f;
#pragma unroll 9
            for (int tt = 0; tt < 63; ++tt)
                acc += emb_W[m * 63 + tt] * gcn_W[(1 + tt) * 32 + j];
        }
        Wfull[k * 32 + j] = acc;
        if (blockIdx.x == 0 && t < 32) {
            float bacc = 0.0f;
            for (int tt = 0; tt < 63; ++tt)
                bacc += emb_b[tt] * gcn_W[(1 + tt) * 32 + t];
            hWbias[t] = bacc;
        }
    } else {
        __shared__ int s[BLK];
        const int K = 7;  // 256*7 = 1792 >= MAXNB
        int v[K]; int sum = 0;
#pragma unroll
        for (int k = 0; k < K; ++k) {
            int i = t * K + k;
            v[k] = (i < NB) ? tot[i] : 0;
            sum += v[k];
        }
        s[t] = sum; __syncthreads();
        for (int st = 1; st < BLK; st <<= 1) {
            int x = (t >= st) ? s[t - st] : 0;
            __syncthreads(); s[t] += x; __syncthreads();
        }
        int ex = (t == 0) ? 0 : s[t - 1];
#pragma unroll
        for (int k = 0; k < K; ++k) {
            int i = t * K + k;
            if (i < NB) base_[i] = ex;
            ex += v[k];
        }
        if (t == BLK - 1) base_[NB] = s[BLK - 1];
    }
}

// kC: SINGLE-PASS scatter. XCD k owns a CONTIGUOUS range of the 367 used
// chunks (46/46/46/46/46/46/46/45) -> per-bucket csrB writes are monotone
// per-XCD sub-runs (R13, clean). Classes staged per-chunk into LDS clsL
// from kl cells (default 2 = obs). Entry = (local_col<<19)|(row<<2)|cls.
__global__ void kC_scatter(const int* __restrict__ row, const int* __restrict__ col,
                           const uint16_t* __restrict__ kl, const int* __restrict__ cnt2,
                           const int* __restrict__ base_,
                           const int* __restrict__ offTT, int* __restrict__ csrB,
                           int n_edges, int NB) {
    __shared__ int cur[MAXNB];
    __shared__ uint8_t clsL[CHK];
    __shared__ int cnt2s[NCB];
    int t = threadIdx.x;
    int nused = (n_edges + CHK - 1) >> CHKSH;   // 367
    int xcd = blockIdx.x & 7, ord = blockIdx.x >> 3;
    int q = nused >> 3, r = nused & 7;
    int len = (xcd < r) ? q + 1 : q;
    if (ord >= len) return;                      // empty-slot block
    int c = (xcd < r) ? xcd * (q + 1) + ord
                      : r * (q + 1) + (xcd - r) * q + ord;
    const int* offrow = offTT + (size_t)c * NB;
    for (int b = t; b < NB; b += BLK) cur[b] = base_[b] + offrow[b];
    for (int i = t; i < CHK; i += BLK) clsL[i] = 2;
    if (t < NCB) cnt2s[t] = cnt2[(size_t)t * NCHUNK + c];
    __syncthreads();
    for (int idx = t; idx < NCB * CELLCAP; idx += BLK) {
        int b2 = idx / CELLCAP, i = idx - b2 * CELLCAP;
        if (i < cnt2s[b2]) {
            uint16_t v = kl[((size_t)c * NCB + b2) * CELLCAP + i];
            clsL[v >> 1] = (uint8_t)(v & 1);
        }
    }
    __syncthreads();
    int e0 = c << CHKSH, e1 = min(e0 + CHK, n_edges);
    for (int e = e0 + t; e < e1; e += BLK) {
        int cc = col[e];
        int pos = atomicAdd(&cur[cc >> 6], 1);
        csrB[pos] = ((cc & 63) << 19) | (row[e] << 2) | clsL[e - e0];
    }
}

// k4f: fused degree + GEMM per 64-node bucket.
__global__ void k4f_gemm(const float* __restrict__ x, const float* __restrict__ Wfull,
                         const float* __restrict__ hWbias, const int* __restrict__ base_,
                         const int* __restrict__ csrB, const float* __restrict__ mw,
                         __half* __restrict__ hWs, int n_nodes) {
    __shared__ float Wl[64 * 32];      // 8KB
    __shared__ float xs[64 * 64];      // 16KB
    __shared__ int ct4[256];           // 1KB
    __shared__ float dv[64];
    int b = blockIdx.x, t = threadIdx.x;
    for (int idx = t; idx < 2048; idx += BLK) Wl[idx] = Wfull[idx];
    if (t < 256) ct4[t] = 0;
    int rowBase = b * 64;
    for (int idx = t; idx < 4096; idx += BLK) {
        int r = rowBase + (idx >> 6);
        xs[idx] = (r < n_nodes) ? x[(size_t)r * 64 + (idx & 63)] : 0.0f;
    }
    __syncthreads();
    int p0 = base_[b], p1 = base_[b + 1];
    for (int p = p0 + t; p < p1; p += BLK) {
        int e = csrB[p];
        atomicAdd(&ct4[((e >> 19) << 2) | (e & 3)], 1);
    }
    __syncthreads();
    if (t < 64) {
        float a = mw[0], bb = mw[1], c3 = mw[2];
        float m = fmaxf(a, fmaxf(bb, c3));
        float ea = __expf(a - m), eb = __expf(bb - m), ec = __expf(c3 - m);
        float inv = 1.0f / (ea + eb + ec);
        float deg = (ea * inv) * (float)ct4[t * 4]
                  + (eb * inv) * (float)ct4[t * 4 + 1]
                  + (ec * inv) * (float)ct4[t * 4 + 2]
                  + (float)ct4[t * 4 + 3]
                  + 1.0f;
        dv[t] = rsqrtf(deg);
    }
    __syncthreads();
    int j = t & 31, lr = t >> 5;
#pragma unroll
    for (int k8 = 0; k8 < 8; ++k8) {
        int r = lr + 8 * k8;
        int n = rowBase + r;
        if (n < n_nodes) {
            float acc = hWbias[j];
#pragma unroll
            for (int k = 0; k < 64; ++k)
                acc += xs[r * 64 + k] * Wl[k * 32 + j];
            hWs[(size_t)n * 32 + j] = __float2half(dv[r] * acc);
        }
    }
}

// kD: per-bucket consumer. Stage csrB segment in LDS (read once), count,
// counting-sort from LDS, per-node register gather (16 lanes/node, half2),
// relu, run-length pool.
__global__ void kD_gather(const int* __restrict__ base_, const int* __restrict__ csrB,
                          const __half2* __restrict__ hws2,
                          const float* __restrict__ mw, const float* __restrict__ gcn_b,
                          const int* __restrict__ batch, float* __restrict__ pooled,
                          int n_nodes) {
    __shared__ int ent[ENTCAP];
    __shared__ int raw[ENTCAP];       // staged csrB segment (csrB read ONCE)
    __shared__ float res[64 * 33];
    __shared__ int ct4[256];
    __shared__ int ct[64], st[64], cur[64];
    __shared__ float dl[64], gb[32];
    __shared__ int bl[64];
    int b = blockIdx.x, t = threadIdx.x;
    if (t < 256) ct4[t] = 0;
    if (t < 64) {
        int n = b * 64 + t;
        bl[t] = (n < n_nodes) ? batch[n] : -1;
    }
    if (t < 32) gb[t] = gcn_b[t];
    __syncthreads();
    int p0 = base_[b], p1 = base_[b + 1];
    int m = min(p1 - p0, ENTCAP);     // clamp (14 sigma margin, never hit)
    for (int i = t; i < m; i += BLK) {
        int e = csrB[p0 + i];
        raw[i] = e;
        atomicAdd(&ct4[((e >> 19) << 2) | (e & 3)], 1);
    }
    __syncthreads();
    float a = mw[0], bb = mw[1], c3 = mw[2];
    float mx = fmaxf(a, fmaxf(bb, c3));
    float ea = __expf(a - mx), eb = __expf(bb - mx), ec = __expf(c3 - mx);
    float inv = 1.0f / (ea + eb + ec);
    float w0 = ea * inv, w1 = eb * inv, w2 = ec * inv;
    if (t < 64) {
        int c0 = ct4[t * 4], c1 = ct4[t * 4 + 1], c2 = ct4[t * 4 + 2], c33 = ct4[t * 4 + 3];
        ct[t] = c0 + c1 + c2 + c33;
        dl[t] = rsqrtf(w0 * (float)c0 + w1 * (float)c1 + w2 * (float)c2
                       + (float)c33 + 1.0f);
    }
    __syncthreads();
    if (t < 64) st[t] = ct[t];
    __syncthreads();
    for (int off = 1; off < 64; off <<= 1) {
        int v = (t < 64 && t >= off) ? st[t - off] : 0;
        __syncthreads();
        if (t < 64) st[t] += v;
        __syncthreads();
    }
    if (t < 64) { st[t] -= ct[t]; cur[t] = st[t]; }
    __syncthreads();
    for (int i = t; i < m; i += BLK) {
        int e = raw[i];
        int pos = atomicAdd(&cur[e >> 19], 1);
        ent[pos] = e;
    }
    __syncthreads();
    int grp = t >> 4, j2 = t & 15;
#pragma unroll
    for (int idx = 0; idx < 4; ++idx) {
        int lc = grp + 16 * idx;
        int n = b * 64 + lc;
        float rx = 0.0f, ry = 0.0f;
        if (n < n_nodes) {
            int s = st[lc], end = s + ct[lc];
            float ax = 0.0f, ay = 0.0f;
            int p = s;
            for (; p + 8 <= end; p += 8) {
                int e0 = ent[p],     e1 = ent[p + 1], e2 = ent[p + 2], e3 = ent[p + 3];
                int e4 = ent[p + 4], e5 = ent[p + 5], e6 = ent[p + 6], e7 = ent[p + 7];
                __half2 h0 = hws2[(size_t)((e0 >> 2) & 0x1FFFF) * 16 + j2];
                __half2 h1 = hws2[(size_t)((e1 >> 2) & 0x1FFFF) * 16 + j2];
                __half2 h2 = hws2[(size_t)((e2 >> 2) & 0x1FFFF) * 16 + j2];
                __half2 h3 = hws2[(size_t)((e3 >> 2) & 0x1FFFF) * 16 + j2];
                __half2 h4 = hws2[(size_t)((e4 >> 2) & 0x1FFFF) * 16 + j2];
                __half2 h5 = hws2[(size_t)((e5 >> 2) & 0x1FFFF) * 16 + j2];
                __half2 h6 = hws2[(size_t)((e6 >> 2) & 0x1FFFF) * 16 + j2];
                __half2 h7 = hws2[(size_t)((e7 >> 2) & 0x1FFFF) * 16 + j2];
                float f0 = ((e0 & 3) == 0) ? w0 : (((e0 & 3) == 1) ? w1 : w2);
                float f1 = ((e1 & 3) == 0) ? w0 : (((e1 & 3) == 1) ? w1 : w2);
                float f2 = ((e2 & 3) == 0) ? w0 : (((e2 & 3) == 1) ? w1 : w2);
                float f3 = ((e3 & 3) == 0) ? w0 : (((e3 & 3) == 1) ? w1 : w2);
                float f4 = ((e4 & 3) == 0) ? w0 : (((e4 & 3) == 1) ? w1 : w2);
                float f5 = ((e5 & 3) == 0) ? w0 : (((e5 & 3) == 1) ? w1 : w2);
                float f6 = ((e6 & 3) == 0) ? w0 : (((e6 & 3) == 1) ? w1 : w2);
                float f7 = ((e7 & 3) == 0) ? w0 : (((e7 & 3) == 1) ? w1 : w2);
                float2 g0 = __half22float2(h0), g1 = __half22float2(h1);
                float2 g2 = __half22float2(h2), g3 = __half22float2(h3);
                float2 g4 = __half22float2(h4), g5 = __half22float2(h5);
                float2 g6 = __half22float2(h6), g7 = __half22float2(h7);
                ax += f0 * g0.x + f1 * g1.x + f2 * g2.x + f3 * g3.x
                    + f4 * g4.x + f5 * g5.x + f6 * g6.x + f7 * g7.x;
                ay += f0 * g0.y + f1 * g1.y + f2 * g2.y + f3 * g3.y
                    + f4 * g4.y + f5 * g5.y + f6 * g6.y + f7 * g7.y;
            }
            for (; p < end; ++p) {
                int e0 = ent[p];
                __half2 h0 = hws2[(size_t)((e0 >> 2) & 0x1FFFF) * 16 + j2];
                float f0 = ((e0 & 3) == 0) ? w0 : (((e0 & 3) == 1) ? w1 : w2);
                float2 g0 = __half22float2(h0);
                ax += f0 * g0.x; ay += f0 * g0.y;
            }
            float2 self = __half22float2(hws2[(size_t)n * 16 + j2]);
            float di = dl[lc];
            rx = fmaxf(di * (ax + self.x) + gb[2 * j2], 0.0f);
            ry = fmaxf(di * (ay + self.y) + gb[2 * j2 + 1], 0.0f);
        }
        res[lc * 33 + 2 * j2]     = rx;
        res[lc * 33 + 2 * j2 + 1] = ry;
    }
    __syncthreads();
    if (t < 32) {
        int j = t;
        float sum = 0.0f; int g0 = bl[0];
        for (int lc = 0; lc < 64; ++lc) {
            if (bl[lc] < 0) break;
            float val = res[lc * 33 + j];
            if (bl[lc] != g0) { atomicAdd(&pooled[g0 * 32 + j], sum); sum = 0.0f; g0 = bl[lc]; }
            sum += val;
        }
        if (g0 >= 0) atomicAdd(&pooled[g0 * 32 + j], sum);
    }
}

// k7: head: z = relu(pooled @ fc1_W + fc1_b); out = z @ out_W + out_b
__global__ void k7_head(const float* __restrict__ pooled, const float* __restrict__ fc1_W,
                        const float* __restrict__ fc1_b, const float* __restrict__ out_W,
                        const float* __restrict__ out_b, float* __restrict__ out,
                        int n_graphs) {
    __shared__ float Wl[32 * 32];
    __shared__ float bl[32];
    __shared__ float owl[32];
    int t = threadIdx.x;
    for (int idx = t; idx < 1024; idx += BLK) Wl[idx] = fc1_W[idx];
    if (t < 32) { bl[t] = fc1_b[t]; owl[t] = out_W[t]; }
    __syncthreads();
    if (t < n_graphs) {
        float p[32];
#pragma unroll
        for (int k = 0; k < 32; ++k) p[k] = pooled[t * 32 + k];
        float acc = 0.0f;
        for (int j = 0; j < 32; ++j) {
            float z = bl[j];
#pragma unroll
            for (int k = 0; k < 32; ++k) z += p[k] * Wl[k * 32 + j];
            z = fmaxf(z, 0.0f);
            acc += z * owl[j];
        }
        out[t] = acc + out_b[0];
    }
}

static inline size_t align_up(size_t v, size_t a) { return (v + a - 1) & ~(a - 1); }

extern "C" void kernel_launch(void* const* d_in, const int* in_sizes, int n_in,
                              void* d_out, int out_size, void* d_ws, size_t ws_size,
                              hipStream_t stream) {
    const float* x     = (const float*)d_in[0];
    const int*   ei    = (const int*)d_in[1];
    const int*   batch = (const int*)d_in[2];
    const int*   km    = (const int*)d_in[3];
    const int*   um    = (const int*)d_in[4];
    const int*   om    = (const int*)d_in[5];
    const float* mw    = (const float*)d_in[6];
    const float* emb_W = (const float*)d_in[7];
    const float* emb_b = (const float*)d_in[8];
    const float* gcn_W = (const float*)d_in[9];
    const float* gcn_b = (const float*)d_in[10];
    const float* fc1_W = (const float*)d_in[11];
    const float* fc1_b = (const float*)d_in[12];
    const float* out_W = (const float*)d_in[13];
    const float* out_b = (const float*)d_in[14];
    (void)om;

    const int n_nodes  = in_sizes[0] / 64;
    const int n_edges  = in_sizes[1] / 2;
    const int s0 = in_sizes[3], s1 = in_sizes[4];
    const int n_graphs = out_size;  // 256

    const int* row = ei;
    const int* col = ei + n_edges;

    const int NB  = (n_nodes + 63) >> 6;   // 1563 buckets of 64 nodes
    const int NGB = (NB + 15) / 16;        // kB2 blocks

    // ---- workspace layout (~28.5 MB) ----
    char* base = (char*)d_ws;
    float*   pooled = (float*)base;   base += (size_t)n_graphs * 32 * 4;   // zeroed
    int*     cnt    = (int*)base;     base += (size_t)NCHUNK * NB * 4;     // 3.2 MB
    int*     offTT  = (int*)base;     base += (size_t)NCHUNK * NB * 4;     // 3.2 MB
    int*     tot    = (int*)base;     base += (size_t)NB * 4;
    int*     base_  = (int*)base;     base += (size_t)(NB + 1) * 4;
    float*   Wfull  = (float*)base;   base += 2048 * 4;
    float*   hWbias = (float*)base;   base += 32 * 4;
    int*     cnt2   = (int*)base;     base += (size_t)NCB * NCHUNK * 4;    // 256 KB
    int*     csrB   = (int*)base;     base += (size_t)n_edges * 4;         // 12 MB
    base = (char*)align_up((size_t)base, 64);
    // UNION region: kl (12.6 MB, live kA1..kC) overlaps hWs (6.4 MB, live
    // k4f..kD). kC finishes before k4f starts (stream order) -> safe.
    uint16_t* kl  = (uint16_t*)base;
    __half*   hWs = (__half*)base;
    base += (size_t)NCHUNK * NCB * CELLCAP * 2;                            // 12.6 MB

    hipMemsetAsync(pooled, 0, (size_t)n_graphs * 32 * 4, stream);

    kA1<<<NCHUNK + NCB, BLK, 0, stream>>>(col, cnt, n_edges, NB, km, um, s0, s1,
                                          kl, cnt2);
    kB2<<<NGB, BLK, 0, stream>>>(cnt, offTT, tot, NB);
    kBase3<<<9, BLK, 0, stream>>>(tot, base_, NB, emb_W, emb_b, gcn_W, Wfull, hWbias);
    kC_scatter<<<NCHUNK, BLK, 0, stream>>>(row, col, kl, cnt2, base_, offTT, csrB,
                                           n_edges, NB);
    k4f_gemm<<<NB, BLK, 0, stream>>>(x, Wfull, hWbias, base_, csrB, mw, hWs, n_nodes);
    kD_gather<<<NB, BLK, 0, stream>>>(base_, csrB, (const __half2*)hWs, mw,
                                      gcn_b, batch, pooled, n_nodes);
    k7_head<<<1, BLK, 0, stream>>>(pooled, fc1_W, fc1_b, out_W, out_b, (float*)d_out, n_graphs);
}

// Round 6
// 300.294 us; speedup vs baseline: 1.3292x; 1.0459x over previous
//
#include <hip/hip_runtime.h>
#include <hip/hip_fp16.h>
#include <stdint.h>

// GCN forward. N=100000, E=3000000, G=256, F_IN=64, NHID=32.
// R1: 96M global scatter-atomics = L2 atomic ceiling (312us) -> gather.
// R2: naive CSR build = 16x write amplification (random sub-line stores).
// R6: small hot global atomic arrays = 32B line ping-pong per op.
// R9: nontemporal_store is write-through (~56B per random sub-line store).
// R13: kC single pass, XCD-contiguous chunk ranges -> monotone per-bucket
//     sub-runs (still ~2.6x write amp at boundaries per R17 counters).
// R14 FAILED: atomicOr scatter = same ~32B/op sector cost + throttle.
// R15: default cls=2 + scatter only km/um: kA1 65->54us. 274.5us total.
// R16 FAILED: XCD-pinned ewc scatter. WRITE unchanged; dirty random
//     sub-line stores do NOT accumulate in L2. Clean scatter requires
//     line-private dense writes.
// R17: kl-cell class transpose (192B single-writer cells) + CHK=8192.
//     kC 68.8us (367-block tail imbalance: 2nd wave 43% full) and
//     kD 66us (raw[] staging cost occupancy 43->32% while FETCH was
//     UNCHANGED -> csrB re-read was already L2-hit). kA1 unmeasured.
// R18 (this round): revert kD to R15 form; CHK=4096 (733 kC blocks,
//     2.86/CU); cnt/offTT at 4096-gran as uint16 (same byte volume);
//     kl cells at 4096-gran, CELLCAP 56. kA1 kl experiment still live.

#define BLK 256
#define NCHUNK 1024         // chunk slots (power-of-2 CHK each)
#define CHKSH 12
#define CHK 4096            // edges per chunk; used chunks = ceil(E/4096)=733
#define NCB 128             // class-bucketing writer blocks
#define CELLCAP 56          // entries per (chunk,block) cell; lambda~21, 7.5sig
#define MAXNB 1600          // max node buckets (N<=102400)
#define ENTCAP 2560         // per-bucket LDS entries (lambda=1920, 14 sigma)

// kA1: fused. Blocks [0,NCHUNK): per-chunk node-bucket histogram (LDS),
// cnt stored uint16. Blocks [NCHUNK, NCHUNK+NCB): class bucketing into
// PRIVATE cells kl[chunk][b][0..56) = (local_e<<1 | cls); cnt2 fill counts.
__global__ void kA1(const int* __restrict__ col, uint16_t* __restrict__ cnt,
                    int n_edges, int NB,
                    const int* __restrict__ km, const int* __restrict__ um,
                    int s0, int s1,
                    uint16_t* __restrict__ kl, int* __restrict__ cnt2) {
    int t = threadIdx.x;
    if (blockIdx.x < NCHUNK) {
        __shared__ int lh[MAXNB];
        int c = blockIdx.x;
        for (int b = t; b < NB; b += BLK) lh[b] = 0;
        __syncthreads();
        int e0 = c << CHKSH, e1 = min(e0 + CHK, n_edges);
        for (int e = e0 + t; e < e1; e += BLK) atomicAdd(&lh[col[e] >> 6], 1);
        __syncthreads();
        for (int b = t; b < NB; b += BLK) cnt[(size_t)c * NB + b] = (uint16_t)lh[b];
    } else {
        __shared__ int cur2[NCHUNK];
        int b = blockIdx.x - NCHUNK;          // [0, NCB)
        for (int i = t; i < NCHUNK; i += BLK) cur2[i] = 0;
        __syncthreads();
        int total = s0 + s1;
        int slice = (total + NCB - 1) / NCB;
        int i0 = b * slice, i1 = min(i0 + slice, total);
        for (int i = i0 + t; i < i1; i += BLK) {
            int e, cls;
            if (i < s0) { e = km[i];      cls = 0; }
            else        { e = um[i - s0]; cls = 1; }
            int bu = e >> CHKSH;
            int pos = atomicAdd(&cur2[bu], 1);
            if (pos < CELLCAP)
                kl[((size_t)bu * NCB + b) * CELLCAP + pos] =
                    (uint16_t)(((e & (CHK - 1)) << 1) | cls);
        }
        __syncthreads();
        for (int i = t; i < NCHUNK; i += BLK) cnt2[(size_t)b * NCHUNK + i] = cur2[i];
    }
}

// kB2: 16 node-buckets per block. Tile cnt (uint16) through LDS, scan over
// 1024 chunks (16 segs x 64), write offTT (uint16) TRANSPOSED.
__global__ void kB2(const uint16_t* __restrict__ cnt, uint16_t* __restrict__ offTT,
                    int* __restrict__ tot, int NB) {
    __shared__ uint16_t tile[NCHUNK * 16];   // 32KB
    __shared__ int segs[16][17];
    int t = threadIdx.x;
    int b0 = blockIdx.x * 16;
    for (int idx = t; idx < NCHUNK * 16; idx += BLK) {
        int c = idx >> 4, b = idx & 15;
        tile[idx] = (b0 + b < NB) ? cnt[(size_t)c * NB + b0 + b] : (uint16_t)0;
    }
    __syncthreads();
    int b = t & 15, seg = t >> 4;            // 16 segs x 16 buckets
    int psum = 0;
#pragma unroll
    for (int k = 0; k < 64; ++k) psum += (int)tile[(seg * 64 + k) * 16 + b];
    segs[seg][b] = psum;
    __syncthreads();
    int ex = 0;
    for (int ss = 0; ss < seg; ++ss) ex += segs[ss][b];
    int run = ex;
#pragma unroll
    for (int k = 0; k < 64; ++k) {
        int c = seg * 64 + k;
        if (b0 + b < NB) offTT[(size_t)c * NB + b0 + b] = (uint16_t)run;
        run += (int)tile[c * 16 + b];
    }
    if (seg == 15 && b0 + b < NB) tot[b0 + b] = run;
}

// kBase3: fused. Blocks 0..7: fold emb through gcn (Wfull, hWbias).
// Block 8: exclusive scan of tot[NB] -> base_[0..NB].
__global__ void kBase3(const int* __restrict__ tot, int* __restrict__ base_, int NB,
                       const float* __restrict__ emb_W, const float* __restrict__ emb_b,
                       const float* __restrict__ gcn_W,
                       float* __restrict__ Wfull, float* __restrict__ hWbias) {
    int t = threadIdx.x;
    if (blockIdx.x < 8) {
        int k = blockIdx.x * 8 + (t >> 5), j = t & 31;
        float acc;
        if (k == 0) {
            acc = gcn_W[j];
        } else {
            int m = k - 1;
            acc = 0.0f;
#pragma unroll 9
            for (int tt = 0; tt < 63; ++tt)
                acc += emb_W[m * 63 + tt] * gcn_W[(1 + tt) * 32 + j];
        }
        Wfull[k * 32 + j] = acc;
        if (blockIdx.x == 0 && t < 32) {
            float bacc = 0.0f;
            for (int tt = 0; tt < 63; ++tt)
                bacc += emb_b[tt] * gcn_W[(1 + tt) * 32 + t];
            hWbias[t] = bacc;
        }
    } else {
        __shared__ int s[BLK];
        const int K = 7;  // 256*7 = 1792 >= MAXNB
        int v[K]; int sum = 0;
#pragma unroll
        for (int k = 0; k < K; ++k) {
            int i = t * K + k;
            v[k] = (i < NB) ? tot[i] : 0;
            sum += v[k];
        }
        s[t] = sum; __syncthreads();
        for (int st = 1; st < BLK; st <<= 1) {
            int x = (t >= st) ? s[t - st] : 0;
            __syncthreads(); s[t] += x; __syncthreads();
        }
        int ex = (t == 0) ? 0 : s[t - 1];
#pragma unroll
        for (int k = 0; k < K; ++k) {
            int i = t * K + k;
            if (i < NB) base_[i] = ex;
            ex += v[k];
        }
        if (t == BLK - 1) base_[NB] = s[BLK - 1];
    }
}

// kC: SINGLE-PASS scatter. XCD k owns a CONTIGUOUS range of the 733 used
// chunks -> per-bucket csrB writes are monotone per-XCD sub-runs (R13).
// Classes staged per-chunk into LDS clsL from kl cells (default 2 = obs).
// Entry = (local_col<<19)|(row<<2)|cls.
__global__ void kC_scatter(const int* __restrict__ row, const int* __restrict__ col,
                           const uint16_t* __restrict__ kl, const int* __restrict__ cnt2,
                           const int* __restrict__ base_,
                           const uint16_t* __restrict__ offTT, int* __restrict__ csrB,
                           int n_edges, int NB) {
    __shared__ int cur[MAXNB];
    __shared__ uint8_t clsL[CHK];
    __shared__ int cnt2s[NCB];
    int t = threadIdx.x;
    int nused = (n_edges + CHK - 1) >> CHKSH;   // 733
    int xcd = blockIdx.x & 7, ord = blockIdx.x >> 3;
    int q = nused >> 3, r = nused & 7;
    int len = (xcd < r) ? q + 1 : q;
    if (ord >= len) return;                      // empty-slot block
    int c = (xcd < r) ? xcd * (q + 1) + ord
                      : r * (q + 1) + (xcd - r) * q + ord;
    const uint16_t* offrow = offTT + (size_t)c * NB;
    for (int b = t; b < NB; b += BLK) cur[b] = base_[b] + (int)offrow[b];
    for (int i = t; i < CHK; i += BLK) clsL[i] = 2;
    if (t < NCB) cnt2s[t] = cnt2[(size_t)t * NCHUNK + c];
    __syncthreads();
    for (int idx = t; idx < NCB * CELLCAP; idx += BLK) {
        int b2 = idx / CELLCAP, i = idx - b2 * CELLCAP;
        if (i < cnt2s[b2]) {
            uint16_t v = kl[((size_t)c * NCB + b2) * CELLCAP + i];
            clsL[v >> 1] = (uint8_t)(v & 1);
        }
    }
    __syncthreads();
    int e0 = c << CHKSH, e1 = min(e0 + CHK, n_edges);
    for (int e = e0 + t; e < e1; e += BLK) {
        int cc = col[e];
        int pos = atomicAdd(&cur[cc >> 6], 1);
        csrB[pos] = ((cc & 63) << 19) | (row[e] << 2) | clsL[e - e0];
    }
}

// k4f: fused degree + GEMM per 64-node bucket.
__global__ void k4f_gemm(const float* __restrict__ x, const float* __restrict__ Wfull,
                         const float* __restrict__ hWbias, const int* __restrict__ base_,
                         const int* __restrict__ csrB, const float* __restrict__ mw,
                         __half* __restrict__ hWs, int n_nodes) {
    __shared__ float Wl[64 * 32];      // 8KB
    __shared__ float xs[64 * 64];      // 16KB
    __shared__ int ct4[256];           // 1KB
    __shared__ float dv[64];
    int b = blockIdx.x, t = threadIdx.x;
    for (int idx = t; idx < 2048; idx += BLK) Wl[idx] = Wfull[idx];
    if (t < 256) ct4[t] = 0;
    int rowBase = b * 64;
    for (int idx = t; idx < 4096; idx += BLK) {
        int r = rowBase + (idx >> 6);
        xs[idx] = (r < n_nodes) ? x[(size_t)r * 64 + (idx & 63)] : 0.0f;
    }
    __syncthreads();
    int p0 = base_[b], p1 = base_[b + 1];
    for (int p = p0 + t; p < p1; p += BLK) {
        int e = csrB[p];
        atomicAdd(&ct4[((e >> 19) << 2) | (e & 3)], 1);
    }
    __syncthreads();
    if (t < 64) {
        float a = mw[0], bb = mw[1], c3 = mw[2];
        float m = fmaxf(a, fmaxf(bb, c3));
        float ea = __expf(a - m), eb = __expf(bb - m), ec = __expf(c3 - m);
        float inv = 1.0f / (ea + eb + ec);
        float deg = (ea * inv) * (float)ct4[t * 4]
                  + (eb * inv) * (float)ct4[t * 4 + 1]
                  + (ec * inv) * (float)ct4[t * 4 + 2]
                  + (float)ct4[t * 4 + 3]
                  + 1.0f;
        dv[t] = rsqrtf(deg);
    }
    __syncthreads();
    int j = t & 31, lr = t >> 5;
#pragma unroll
    for (int k8 = 0; k8 < 8; ++k8) {
        int r = lr + 8 * k8;
        int n = rowBase + r;
        if (n < n_nodes) {
            float acc = hWbias[j];
#pragma unroll
            for (int k = 0; k < 64; ++k)
                acc += xs[r * 64 + k] * Wl[k * 32 + j];
            hWs[(size_t)n * 32 + j] = __float2half(dv[r] * acc);
        }
    }
}

// kD: per-bucket consumer (R15 form — csrB re-read is L2-hit, raw[] staging
// proved an occupancy loss in R17). Counting-sort edges into LDS per-node
// lists, per-node register gather (16 lanes/node, half2, 8 in flight),
// relu, run-length pool.
__global__ void kD_gather(const int* __restrict__ base_, const int* __restrict__ csrB,
                          const __half2* __restrict__ hws2,
                          const float* __restrict__ mw, const float* __restrict__ gcn_b,
                          const int* __restrict__ batch, float* __restrict__ pooled,
                          int n_nodes) {
    __shared__ int ent[ENTCAP];
    __shared__ float res[64 * 33];
    __shared__ int ct4[256];
    __shared__ int ct[64], st[64], cur[64];
    __shared__ float dl[64], gb[32];
    __shared__ int bl[64];
    int b = blockIdx.x, t = threadIdx.x;
    if (t < 256) ct4[t] = 0;
    if (t < 64) {
        int n = b * 64 + t;
        bl[t] = (n < n_nodes) ? batch[n] : -1;
    }
    if (t < 32) gb[t] = gcn_b[t];
    __syncthreads();
    int p0 = base_[b], p1 = base_[b + 1];
    int m = min(p1 - p0, ENTCAP);     // clamp (14 sigma margin, never hit)
    int p1c = p0 + m;
    for (int p = p0 + t; p < p1c; p += BLK) {
        int e = csrB[p];
        atomicAdd(&ct4[((e >> 19) << 2) | (e & 3)], 1);
    }
    __syncthreads();
    float a = mw[0], bb = mw[1], c3 = mw[2];
    float mx = fmaxf(a, fmaxf(bb, c3));
    float ea = __expf(a - mx), eb = __expf(bb - mx), ec = __expf(c3 - mx);
    float inv = 1.0f / (ea + eb + ec);
    float w0 = ea * inv, w1 = eb * inv, w2 = ec * inv;
    if (t < 64) {
        int c0 = ct4[t * 4], c1 = ct4[t * 4 + 1], c2 = ct4[t * 4 + 2], c33 = ct4[t * 4 + 3];
        ct[t] = c0 + c1 + c2 + c33;
        dl[t] = rsqrtf(w0 * (float)c0 + w1 * (float)c1 + w2 * (float)c2
                       + (float)c33 + 1.0f);
    }
    __syncthreads();
    if (t < 64) st[t] = ct[t];
    __syncthreads();
    for (int off = 1; off < 64; off <<= 1) {
        int v = (t < 64 && t >= off) ? st[t - off] : 0;
        __syncthreads();
        if (t < 64) st[t] += v;
        __syncthreads();
    }
    if (t < 64) { st[t] -= ct[t]; cur[t] = st[t]; }
    __syncthreads();
    for (int p = p0 + t; p < p1c; p += BLK) {
        int e = csrB[p];
        int pos = atomicAdd(&cur[e >> 19], 1);
        ent[pos] = e;
    }
    __syncthreads();
    int grp = t >> 4, j2 = t & 15;
#pragma unroll
    for (int idx = 0; idx < 4; ++idx) {
        int lc = grp + 16 * idx;
        int n = b * 64 + lc;
        float rx = 0.0f, ry = 0.0f;
        if (n < n_nodes) {
            int s = st[lc], end = s + ct[lc];
            float ax = 0.0f, ay = 0.0f;
            int p = s;
            for (; p + 8 <= end; p += 8) {
                int e0 = ent[p],     e1 = ent[p + 1], e2 = ent[p + 2], e3 = ent[p + 3];
                int e4 = ent[p + 4], e5 = ent[p + 5], e6 = ent[p + 6], e7 = ent[p + 7];
                __half2 h0 = hws2[(size_t)((e0 >> 2) & 0x1FFFF) * 16 + j2];
                __half2 h1 = hws2[(size_t)((e1 >> 2) & 0x1FFFF) * 16 + j2];
                __half2 h2 = hws2[(size_t)((e2 >> 2) & 0x1FFFF) * 16 + j2];
                __half2 h3 = hws2[(size_t)((e3 >> 2) & 0x1FFFF) * 16 + j2];
                __half2 h4 = hws2[(size_t)((e4 >> 2) & 0x1FFFF) * 16 + j2];
                __half2 h5 = hws2[(size_t)((e5 >> 2) & 0x1FFFF) * 16 + j2];
                __half2 h6 = hws2[(size_t)((e6 >> 2) & 0x1FFFF) * 16 + j2];
                __half2 h7 = hws2[(size_t)((e7 >> 2) & 0x1FFFF) * 16 + j2];
                float f0 = ((e0 & 3) == 0) ? w0 : (((e0 & 3) == 1) ? w1 : w2);
                float f1 = ((e1 & 3) == 0) ? w0 : (((e1 & 3) == 1) ? w1 : w2);
                float f2 = ((e2 & 3) == 0) ? w0 : (((e2 & 3) == 1) ? w1 : w2);
                float f3 = ((e3 & 3) == 0) ? w0 : (((e3 & 3) == 1) ? w1 : w2);
                float f4 = ((e4 & 3) == 0) ? w0 : (((e4 & 3) == 1) ? w1 : w2);
                float f5 = ((e5 & 3) == 0) ? w0 : (((e5 & 3) == 1) ? w1 : w2);
                float f6 = ((e6 & 3) == 0) ? w0 : (((e6 & 3) == 1) ? w1 : w2);
                float f7 = ((e7 & 3) == 0) ? w0 : (((e7 & 3) == 1) ? w1 : w2);
                float2 g0 = __half22float2(h0), g1 = __half22float2(h1);
                float2 g2 = __half22float2(h2), g3 = __half22float2(h3);
                float2 g4 = __half22float2(h4), g5 = __half22float2(h5);
                float2 g6 = __half22float2(h6), g7 = __half22float2(h7);
                ax += f0 * g0.x + f1 * g1.x + f2 * g2.x + f3 * g3.x
                    + f4 * g4.x + f5 * g5.x + f6 * g6.x + f7 * g7.x;
                ay += f0 * g0.y + f1 * g1.y + f2 * g2.y + f3 * g3.y
                    + f4 * g4.y + f5 * g5.y + f6 * g6.y + f7 * g7.y;
            }
            for (; p < end; ++p) {
                int e0 = ent[p];
                __half2 h0 = hws2[(size_t)((e0 >> 2) & 0x1FFFF) * 16 + j2];
                float f0 = ((e0 & 3) == 0) ? w0 : (((e0 & 3) == 1) ? w1 : w2);
                float2 g0 = __half22float2(h0);
                ax += f0 * g0.x; ay += f0 * g0.y;
            }
            float2 self = __half22float2(hws2[(size_t)n * 16 + j2]);
            float di = dl[lc];
            rx = fmaxf(di * (ax + self.x) + gb[2 * j2], 0.0f);
            ry = fmaxf(di * (ay + self.y) + gb[2 * j2 + 1], 0.0f);
        }
        res[lc * 33 + 2 * j2]     = rx;
        res[lc * 33 + 2 * j2 + 1] = ry;
    }
    __syncthreads();
    if (t < 32) {
        int j = t;
        float sum = 0.0f; int g0 = bl[0];
        for (int lc = 0; lc < 64; ++lc) {
            if (bl[lc] < 0) break;
            float val = res[lc * 33 + j];
            if (bl[lc] != g0) { atomicAdd(&pooled[g0 * 32 + j], sum); sum = 0.0f; g0 = bl[lc]; }
            sum += val;
        }
        if (g0 >= 0) atomicAdd(&pooled[g0 * 32 + j], sum);
    }
}

// k7: head: z = relu(pooled @ fc1_W + fc1_b); out = z @ out_W + out_b
__global__ void k7_head(const float* __restrict__ pooled, const float* __restrict__ fc1_W,
                        const float* __restrict__ fc1_b, const float* __restrict__ out_W,
                        const float* __restrict__ out_b, float* __restrict__ out,
                        int n_graphs) {
    __shared__ float Wl[32 * 32];
    __shared__ float bl[32];
    __shared__ float owl[32];
    int t = threadIdx.x;
    for (int idx = t; idx < 1024; idx += BLK) Wl[idx] = fc1_W[idx];
    if (t < 32) { bl[t] = fc1_b[t]; owl[t] = out_W[t]; }
    __syncthreads();
    if (t < n_graphs) {
        float p[32];
#pragma unroll
        for (int k = 0; k < 32; ++k) p[k] = pooled[t * 32 + k];
        float acc = 0.0f;
        for (int j = 0; j < 32; ++j) {
            float z = bl[j];
#pragma unroll
            for (int k = 0; k < 32; ++k) z += p[k] * Wl[k * 32 + j];
            z = fmaxf(z, 0.0f);
            acc += z * owl[j];
        }
        out[t] = acc + out_b[0];
    }
}

static inline size_t align_up(size_t v, size_t a) { return (v + a - 1) & ~(a - 1); }

extern "C" void kernel_launch(void* const* d_in, const int* in_sizes, int n_in,
                              void* d_out, int out_size, void* d_ws, size_t ws_size,
                              hipStream_t stream) {
    const float* x     = (const float*)d_in[0];
    const int*   ei    = (const int*)d_in[1];
    const int*   batch = (const int*)d_in[2];
    const int*   km    = (const int*)d_in[3];
    const int*   um    = (const int*)d_in[4];
    const int*   om    = (const int*)d_in[5];
    const float* mw    = (const float*)d_in[6];
    const float* emb_W = (const float*)d_in[7];
    const float* emb_b = (const float*)d_in[8];
    const float* gcn_W = (const float*)d_in[9];
    const float* gcn_b = (const float*)d_in[10];
    const float* fc1_W = (const float*)d_in[11];
    const float* fc1_b = (const float*)d_in[12];
    const float* out_W = (const float*)d_in[13];
    const float* out_b = (const float*)d_in[14];
    (void)om;

    const int n_nodes  = in_sizes[0] / 64;
    const int n_edges  = in_sizes[1] / 2;
    const int s0 = in_sizes[3], s1 = in_sizes[4];
    const int n_graphs = out_size;  // 256

    const int* row = ei;
    const int* col = ei + n_edges;

    const int NB  = (n_nodes + 63) >> 6;   // 1563 buckets of 64 nodes
    const int NGB = (NB + 15) / 16;        // kB2 blocks

    // ---- workspace layout (~34 MB) ----
    char* base = (char*)d_ws;
    float*    pooled = (float*)base;    base += (size_t)n_graphs * 32 * 4;   // zeroed
    uint16_t* cnt    = (uint16_t*)base; base += (size_t)NCHUNK * NB * 2;     // 3.2 MB
    uint16_t* offTT  = (uint16_t*)base; base += (size_t)NCHUNK * NB * 2;     // 3.2 MB
    int*      tot    = (int*)base;      base += (size_t)NB * 4;
    int*      base_  = (int*)base;      base += (size_t)(NB + 1) * 4;
    float*    Wfull  = (float*)base;    base += 2048 * 4;
    float*    hWbias = (float*)base;    base += 32 * 4;
    int*      cnt2   = (int*)base;      base += (size_t)NCB * NCHUNK * 4;    // 512 KB
    int*      csrB   = (int*)base;      base += (size_t)n_edges * 4;         // 12 MB
    base = (char*)align_up((size_t)base, 64);
    // UNION region: kl (14.7 MB, live kA1..kC) overlaps hWs (6.4 MB, live
    // k4f..kD). kC finishes before k4f starts (stream order) -> safe.
    uint16_t* kl  = (uint16_t*)base;
    __half*   hWs = (__half*)base;
    base += (size_t)NCHUNK * NCB * CELLCAP * 2;                              // 14.7 MB

    hipMemsetAsync(pooled, 0, (size_t)n_graphs * 32 * 4, stream);

    kA1<<<NCHUNK + NCB, BLK, 0, stream>>>(col, cnt, n_edges, NB, km, um, s0, s1,
                                          kl, cnt2);
    kB2<<<NGB, BLK, 0, stream>>>(cnt, offTT, tot, NB);
    kBase3<<<9, BLK, 0, stream>>>(tot, base_, NB, emb_W, emb_b, gcn_W, Wfull, hWbias);
    kC_scatter<<<NCHUNK, BLK, 0, stream>>>(row, col, kl, cnt2, base_, offTT, csrB,
                                           n_edges, NB);
    k4f_gemm<<<NB, BLK, 0, stream>>>(x, Wfull, hWbias, base_, csrB, mw, hWs, n_nodes);
    kD_gather<<<NB, BLK, 0, stream>>>(base_, csrB, (const __half2*)hWs, mw,
                                      gcn_b, batch, pooled, n_nodes);
    k7_head<<<1, BLK, 0, stream>>>(pooled, fc1_W, fc1_b, out_W, out_b, (float*)d_out, n_graphs);
}

// Round 7
// 287.589 us; speedup vs baseline: 1.3879x; 1.0442x over previous
//
#include <hip/hip_runtime.h>
#include <hip/hip_fp16.h>
#include <stdint.h>

// GCN forward. N=100000, E=3000000, G=256, F_IN=64, NHID=32.
// R1: 96M global scatter-atomics = L2 atomic ceiling (312us) -> gather.
// R2: naive CSR build = 16x write amplification (random sub-line stores).
// R6: small hot global atomic arrays = 32B line ping-pong per op.
// R13: kC single pass, XCD-contiguous chunk ranges -> monotone per-bucket
//     sub-runs (~2.6x residual write amp at boundaries).
// R14 FAILED: atomicOr scatter = same ~32B/op sector cost + throttle.
// R15: default cls=2 + scatter only km/um: 274.5us total.
// R16 FAILED: XCD-pinning doesn't make dirty random sub-line stores
//     accumulate in L2. Clean scatter requires LINE-PRIVATE dense writes.
// R17: kl-cell transpose. kC tail imbalance (367 blocks), kD raw[] staging
//     lost occupancy (43->32%) with FETCH unchanged (csrB re-read = L2 hit).
// R18: CHK=4096, kD reverted. kA1 WRITE 78->14MB: CELL SCATTER IS CLEAN.
//     But kA1 dur UNCHANGED (52.8us): latency-bound on the 128-block class
//     tail (1 wave/SIMD on half the CUs), NOT write-BW. Bytes were never
//     kA1's constraint -- tail parallelism is.
// R19 (this round): NCB 128->384 class blocks, launched FIRST (overlap
//     with histogram stream instead of trailing it). CELLCAP 56->24
//     (Poisson: lambda=7.1, P(>24)~1e-19). kl 14.7->13.5MB.

#define BLK 256
#define NCHUNK 1024         // chunk slots (power-of-2 CHK each)
#define CHKSH 12
#define CHK 4096            // edges per chunk; used chunks = ceil(E/4096)=733
#define NCB 384             // class-bucketing writer blocks (launched first)
#define CELLCAP 24          // entries per (chunk,block) cell; lambda~7.1
#define MAXNB 1600          // max node buckets (N<=102400)
#define ENTCAP 2560         // per-bucket LDS entries (lambda=1920, 14 sigma)

// kA1: fused. Blocks [0,NCB): class bucketing into PRIVATE cells
// kl[chunk][b][0..24) = (local_e<<1 | cls); cnt2 fill counts. Launched
// first so the latency-bound scatter overlaps the histogram stream.
// Blocks [NCB, NCB+NCHUNK): per-chunk node-bucket histogram (LDS), uint16.
__global__ void kA1(const int* __restrict__ col, uint16_t* __restrict__ cnt,
                    int n_edges, int NB,
                    const int* __restrict__ km, const int* __restrict__ um,
                    int s0, int s1,
                    uint16_t* __restrict__ kl, int* __restrict__ cnt2) {
    int t = threadIdx.x;
    if (blockIdx.x >= NCB) {
        __shared__ int lh[MAXNB];
        int c = blockIdx.x - NCB;             // [0, NCHUNK)
        for (int b = t; b < NB; b += BLK) lh[b] = 0;
        __syncthreads();
        int e0 = c << CHKSH, e1 = min(e0 + CHK, n_edges);
        for (int e = e0 + t; e < e1; e += BLK) atomicAdd(&lh[col[e] >> 6], 1);
        __syncthreads();
        for (int b = t; b < NB; b += BLK) cnt[(size_t)c * NB + b] = (uint16_t)lh[b];
    } else {
        __shared__ int cur2[NCHUNK];
        int b = blockIdx.x;                   // [0, NCB)
        for (int i = t; i < NCHUNK; i += BLK) cur2[i] = 0;
        __syncthreads();
        int total = s0 + s1;
        int slice = (total + NCB - 1) / NCB;
        int i0 = b * slice, i1 = min(i0 + slice, total);
        for (int i = i0 + t; i < i1; i += BLK) {
            int e, cls;
            if (i < s0) { e = km[i];      cls = 0; }
            else        { e = um[i - s0]; cls = 1; }
            int bu = e >> CHKSH;
            int pos = atomicAdd(&cur2[bu], 1);
            if (pos < CELLCAP)
                kl[((size_t)bu * NCB + b) * CELLCAP + pos] =
                    (uint16_t)(((e & (CHK - 1)) << 1) | cls);
        }
        __syncthreads();
        for (int i = t; i < NCHUNK; i += BLK) cnt2[(size_t)b * NCHUNK + i] = cur2[i];
    }
}

// kB2: 16 node-buckets per block. Tile cnt (uint16) through LDS, scan over
// 1024 chunks (16 segs x 64), write offTT (uint16) TRANSPOSED.
__global__ void kB2(const uint16_t* __restrict__ cnt, uint16_t* __restrict__ offTT,
                    int* __restrict__ tot, int NB) {
    __shared__ uint16_t tile[NCHUNK * 16];   // 32KB
    __shared__ int segs[16][17];
    int t = threadIdx.x;
    int b0 = blockIdx.x * 16;
    for (int idx = t; idx < NCHUNK * 16; idx += BLK) {
        int c = idx >> 4, b = idx & 15;
        tile[idx] = (b0 + b < NB) ? cnt[(size_t)c * NB + b0 + b] : (uint16_t)0;
    }
    __syncthreads();
    int b = t & 15, seg = t >> 4;            // 16 segs x 16 buckets
    int psum = 0;
#pragma unroll
    for (int k = 0; k < 64; ++k) psum += (int)tile[(seg * 64 + k) * 16 + b];
    segs[seg][b] = psum;
    __syncthreads();
    int ex = 0;
    for (int ss = 0; ss < seg; ++ss) ex += segs[ss][b];
    int run = ex;
#pragma unroll
    for (int k = 0; k < 64; ++k) {
        int c = seg * 64 + k;
        if (b0 + b < NB) offTT[(size_t)c * NB + b0 + b] = (uint16_t)run;
        run += (int)tile[c * 16 + b];
    }
    if (seg == 15 && b0 + b < NB) tot[b0 + b] = run;
}

// kBase3: fused. Blocks 0..7: fold emb through gcn (Wfull, hWbias).
// Block 8: exclusive scan of tot[NB] -> base_[0..NB].
__global__ void kBase3(const int* __restrict__ tot, int* __restrict__ base_, int NB,
                       const float* __restrict__ emb_W, const float* __restrict__ emb_b,
                       const float* __restrict__ gcn_W,
                       float* __restrict__ Wfull, float* __restrict__ hWbias) {
    int t = threadIdx.x;
    if (blockIdx.x < 8) {
        int k = blockIdx.x * 8 + (t >> 5), j = t & 31;
        float acc;
        if (k == 0) {
            acc = gcn_W[j];
        } else {
            int m = k - 1;
            acc = 0.0f;
#pragma unroll 9
            for (int tt = 0; tt < 63; ++tt)
                acc += emb_W[m * 63 + tt] * gcn_W[(1 + tt) * 32 + j];
        }
        Wfull[k * 32 + j] = acc;
        if (blockIdx.x == 0 && t < 32) {
            float bacc = 0.0f;
            for (int tt = 0; tt < 63; ++tt)
                bacc += emb_b[tt] * gcn_W[(1 + tt) * 32 + t];
            hWbias[t] = bacc;
        }
    } else {
        __shared__ int s[BLK];
        const int K = 7;  // 256*7 = 1792 >= MAXNB
        int v[K]; int sum = 0;
#pragma unroll
        for (int k = 0; k < K; ++k) {
            int i = t * K + k;
            v[k] = (i < NB) ? tot[i] : 0;
            sum += v[k];
        }
        s[t] = sum; __syncthreads();
        for (int st = 1; st < BLK; st <<= 1) {
            int x = (t >= st) ? s[t - st] : 0;
            __syncthreads(); s[t] += x; __syncthreads();
        }
        int ex = (t == 0) ? 0 : s[t - 1];
#pragma unroll
        for (int k = 0; k < K; ++k) {
            int i = t * K + k;
            if (i < NB) base_[i] = ex;
            ex += v[k];
        }
        if (t == BLK - 1) base_[NB] = s[BLK - 1];
    }
}

// kC: SINGLE-PASS scatter. XCD k owns a CONTIGUOUS range of the 733 used
// chunks -> per-bucket csrB writes are monotone per-XCD sub-runs (R13).
// Classes staged per-chunk into LDS clsL from kl cells (default 2 = obs).
// Entry = (local_col<<19)|(row<<2)|cls.
__global__ void kC_scatter(const int* __restrict__ row, const int* __restrict__ col,
                           const uint16_t* __restrict__ kl, const int* __restrict__ cnt2,
                           const int* __restrict__ base_,
                           const uint16_t* __restrict__ offTT, int* __restrict__ csrB,
                           int n_edges, int NB) {
    __shared__ int cur[MAXNB];
    __shared__ uint8_t clsL[CHK];
    __shared__ int cnt2s[NCB];
    int t = threadIdx.x;
    int nused = (n_edges + CHK - 1) >> CHKSH;   // 733
    int xcd = blockIdx.x & 7, ord = blockIdx.x >> 3;
    int q = nused >> 3, r = nused & 7;
    int len = (xcd < r) ? q + 1 : q;
    if (ord >= len) return;                      // empty-slot block
    int c = (xcd < r) ? xcd * (q + 1) + ord
                      : r * (q + 1) + (xcd - r) * q + ord;
    const uint16_t* offrow = offTT + (size_t)c * NB;
    for (int b = t; b < NB; b += BLK) cur[b] = base_[b] + (int)offrow[b];
    for (int i = t; i < CHK; i += BLK) clsL[i] = 2;
    for (int i = t; i < NCB; i += BLK) cnt2s[i] = cnt2[(size_t)i * NCHUNK + c];
    __syncthreads();
    for (int idx = t; idx < NCB * CELLCAP; idx += BLK) {
        int b2 = idx / CELLCAP, i = idx - b2 * CELLCAP;
        if (i < cnt2s[b2]) {
            uint16_t v = kl[((size_t)c * NCB + b2) * CELLCAP + i];
            clsL[v >> 1] = (uint8_t)(v & 1);
        }
    }
    __syncthreads();
    int e0 = c << CHKSH, e1 = min(e0 + CHK, n_edges);
    for (int e = e0 + t; e < e1; e += BLK) {
        int cc = col[e];
        int pos = atomicAdd(&cur[cc >> 6], 1);
        csrB[pos] = ((cc & 63) << 19) | (row[e] << 2) | clsL[e - e0];
    }
}

// k4f: fused degree + GEMM per 64-node bucket.
__global__ void k4f_gemm(const float* __restrict__ x, const float* __restrict__ Wfull,
                         const float* __restrict__ hWbias, const int* __restrict__ base_,
                         const int* __restrict__ csrB, const float* __restrict__ mw,
                         __half* __restrict__ hWs, int n_nodes) {
    __shared__ float Wl[64 * 32];      // 8KB
    __shared__ float xs[64 * 64];      // 16KB
    __shared__ int ct4[256];           // 1KB
    __shared__ float dv[64];
    int b = blockIdx.x, t = threadIdx.x;
    for (int idx = t; idx < 2048; idx += BLK) Wl[idx] = Wfull[idx];
    if (t < 256) ct4[t] = 0;
    int rowBase = b * 64;
    for (int idx = t; idx < 4096; idx += BLK) {
        int r = rowBase + (idx >> 6);
        xs[idx] = (r < n_nodes) ? x[(size_t)r * 64 + (idx & 63)] : 0.0f;
    }
    __syncthreads();
    int p0 = base_[b], p1 = base_[b + 1];
    for (int p = p0 + t; p < p1; p += BLK) {
        int e = csrB[p];
        atomicAdd(&ct4[((e >> 19) << 2) | (e & 3)], 1);
    }
    __syncthreads();
    if (t < 64) {
        float a = mw[0], bb = mw[1], c3 = mw[2];
        float m = fmaxf(a, fmaxf(bb, c3));
        float ea = __expf(a - m), eb = __expf(bb - m), ec = __expf(c3 - m);
        float inv = 1.0f / (ea + eb + ec);
        float deg = (ea * inv) * (float)ct4[t * 4]
                  + (eb * inv) * (float)ct4[t * 4 + 1]
                  + (ec * inv) * (float)ct4[t * 4 + 2]
                  + (float)ct4[t * 4 + 3]
                  + 1.0f;
        dv[t] = rsqrtf(deg);
    }
    __syncthreads();
    int j = t & 31, lr = t >> 5;
#pragma unroll
    for (int k8 = 0; k8 < 8; ++k8) {
        int r = lr + 8 * k8;
        int n = rowBase + r;
        if (n < n_nodes) {
            float acc = hWbias[j];
#pragma unroll
            for (int k = 0; k < 64; ++k)
                acc += xs[r * 64 + k] * Wl[k * 32 + j];
            hWs[(size_t)n * 32 + j] = __float2half(dv[r] * acc);
        }
    }
}

// kD: per-bucket consumer (R15 form — csrB re-read is L2-hit). Counting-sort
// edges into LDS per-node lists, per-node register gather (16 lanes/node,
// half2, 8 in flight), relu, run-length pool.
__global__ void kD_gather(const int* __restrict__ base_, const int* __restrict__ csrB,
                          const __half2* __restrict__ hws2,
                          const float* __restrict__ mw, const float* __restrict__ gcn_b,
                          const int* __restrict__ batch, float* __restrict__ pooled,
                          int n_nodes) {
    __shared__ int ent[ENTCAP];
    __shared__ float res[64 * 33];
    __shared__ int ct4[256];
    __shared__ int ct[64], st[64], cur[64];
    __shared__ float dl[64], gb[32];
    __shared__ int bl[64];
    int b = blockIdx.x, t = threadIdx.x;
    if (t < 256) ct4[t] = 0;
    if (t < 64) {
        int n = b * 64 + t;
        bl[t] = (n < n_nodes) ? batch[n] : -1;
    }
    if (t < 32) gb[t] = gcn_b[t];
    __syncthreads();
    int p0 = base_[b], p1 = base_[b + 1];
    int m = min(p1 - p0, ENTCAP);     // clamp (14 sigma margin, never hit)
    int p1c = p0 + m;
    for (int p = p0 + t; p < p1c; p += BLK) {
        int e = csrB[p];
        atomicAdd(&ct4[((e >> 19) << 2) | (e & 3)], 1);
    }
    __syncthreads();
    float a = mw[0], bb = mw[1], c3 = mw[2];
    float mx = fmaxf(a, fmaxf(bb, c3));
    float ea = __expf(a - mx), eb = __expf(bb - mx), ec = __expf(c3 - mx);
    float inv = 1.0f / (ea + eb + ec);
    float w0 = ea * inv, w1 = eb * inv, w2 = ec * inv;
    if (t < 64) {
        int c0 = ct4[t * 4], c1 = ct4[t * 4 + 1], c2 = ct4[t * 4 + 2], c33 = ct4[t * 4 + 3];
        ct[t] = c0 + c1 + c2 + c33;
        dl[t] = rsqrtf(w0 * (float)c0 + w1 * (float)c1 + w2 * (float)c2
                       + (float)c33 + 1.0f);
    }
    __syncthreads();
    if (t < 64) st[t] = ct[t];
    __syncthreads();
    for (int off = 1; off < 64; off <<= 1) {
        int v = (t < 64 && t >= off) ? st[t - off] : 0;
        __syncthreads();
        if (t < 64) st[t] += v;
        __syncthreads();
    }
    if (t < 64) { st[t] -= ct[t]; cur[t] = st[t]; }
    __syncthreads();
    for (int p = p0 + t; p < p1c; p += BLK) {
        int e = csrB[p];
        int pos = atomicAdd(&cur[e >> 19], 1);
        ent[pos] = e;
    }
    __syncthreads();
    int grp = t >> 4, j2 = t & 15;
#pragma unroll
    for (int idx = 0; idx < 4; ++idx) {
        int lc = grp + 16 * idx;
        int n = b * 64 + lc;
        float rx = 0.0f, ry = 0.0f;
        if (n < n_nodes) {
            int s = st[lc], end = s + ct[lc];
            float ax = 0.0f, ay = 0.0f;
            int p = s;
            for (; p + 8 <= end; p += 8) {
                int e0 = ent[p],     e1 = ent[p + 1], e2 = ent[p + 2], e3 = ent[p + 3];
                int e4 = ent[p + 4], e5 = ent[p + 5], e6 = ent[p + 6], e7 = ent[p + 7];
                __half2 h0 = hws2[(size_t)((e0 >> 2) & 0x1FFFF) * 16 + j2];
                __half2 h1 = hws2[(size_t)((e1 >> 2) & 0x1FFFF) * 16 + j2];
                __half2 h2 = hws2[(size_t)((e2 >> 2) & 0x1FFFF) * 16 + j2];
                __half2 h3 = hws2[(size_t)((e3 >> 2) & 0x1FFFF) * 16 + j2];
                __half2 h4 = hws2[(size_t)((e4 >> 2) & 0x1FFFF) * 16 + j2];
                __half2 h5 = hws2[(size_t)((e5 >> 2) & 0x1FFFF) * 16 + j2];
                __half2 h6 = hws2[(size_t)((e6 >> 2) & 0x1FFFF) * 16 + j2];
                __half2 h7 = hws2[(size_t)((e7 >> 2) & 0x1FFFF) * 16 + j2];
                float f0 = ((e0 & 3) == 0) ? w0 : (((e0 & 3) == 1) ? w1 : w2);
                float f1 = ((e1 & 3) == 0) ? w0 : (((e1 & 3) == 1) ? w1 : w2);
                float f2 = ((e2 & 3) == 0) ? w0 : (((e2 & 3) == 1) ? w1 : w2);
                float f3 = ((e3 & 3) == 0) ? w0 : (((e3 & 3) == 1) ? w1 : w2);
                float f4 = ((e4 & 3) == 0) ? w0 : (((e4 & 3) == 1) ? w1 : w2);
                float f5 = ((e5 & 3) == 0) ? w0 : (((e5 & 3) == 1) ? w1 : w2);
                float f6 = ((e6 & 3) == 0) ? w0 : (((e6 & 3) == 1) ? w1 : w2);
                float f7 = ((e7 & 3) == 0) ? w0 : (((e7 & 3) == 1) ? w1 : w2);
                float2 g0 = __half22float2(h0), g1 = __half22float2(h1);
                float2 g2 = __half22float2(h2), g3 = __half22float2(h3);
                float2 g4 = __half22float2(h4), g5 = __half22float2(h5);
                float2 g6 = __half22float2(h6), g7 = __half22float2(h7);
                ax += f0 * g0.x + f1 * g1.x + f2 * g2.x + f3 * g3.x
                    + f4 * g4.x + f5 * g5.x + f6 * g6.x + f7 * g7.x;
                ay += f0 * g0.y + f1 * g1.y + f2 * g2.y + f3 * g3.y
                    + f4 * g4.y + f5 * g5.y + f6 * g6.y + f7 * g7.y;
            }
            for (; p < end; ++p) {
                int e0 = ent[p];
                __half2 h0 = hws2[(size_t)((e0 >> 2) & 0x1FFFF) * 16 + j2];
                float f0 = ((e0 & 3) == 0) ? w0 : (((e0 & 3) == 1) ? w1 : w2);
                float2 g0 = __half22float2(h0);
                ax += f0 * g0.x; ay += f0 * g0.y;
            }
            float2 self = __half22float2(hws2[(size_t)n * 16 + j2]);
            float di = dl[lc];
            rx = fmaxf(di * (ax + self.x) + gb[2 * j2], 0.0f);
            ry = fmaxf(di * (ay + self.y) + gb[2 * j2 + 1], 0.0f);
        }
        res[lc * 33 + 2 * j2]     = rx;
        res[lc * 33 + 2 * j2 + 1] = ry;
    }
    __syncthreads();
    if (t < 32) {
        int j = t;
        float sum = 0.0f; int g0 = bl[0];
        for (int lc = 0; lc < 64; ++lc) {
            if (bl[lc] < 0) break;
            float val = res[lc * 33 + j];
            if (bl[lc] != g0) { atomicAdd(&pooled[g0 * 32 + j], sum); sum = 0.0f; g0 = bl[lc]; }
            sum += val;
        }
        if (g0 >= 0) atomicAdd(&pooled[g0 * 32 + j], sum);
    }
}

// k7: head: z = relu(pooled @ fc1_W + fc1_b); out = z @ out_W + out_b
__global__ void k7_head(const float* __restrict__ pooled, const float* __restrict__ fc1_W,
                        const float* __restrict__ fc1_b, const float* __restrict__ out_W,
                        const float* __restrict__ out_b, float* __restrict__ out,
                        int n_graphs) {
    __shared__ float Wl[32 * 32];
    __shared__ float bl[32];
    __shared__ float owl[32];
    int t = threadIdx.x;
    for (int idx = t; idx < 1024; idx += BLK) Wl[idx] = fc1_W[idx];
    if (t < 32) { bl[t] = fc1_b[t]; owl[t] = out_W[t]; }
    __syncthreads();
    if (t < n_graphs) {
        float p[32];
#pragma unroll
        for (int k = 0; k < 32; ++k) p[k] = pooled[t * 32 + k];
        float acc = 0.0f;
        for (int j = 0; j < 32; ++j) {
            float z = bl[j];
#pragma unroll
            for (int k = 0; k < 32; ++k) z += p[k] * Wl[k * 32 + j];
            z = fmaxf(z, 0.0f);
            acc += z * owl[j];
        }
        out[t] = acc + out_b[0];
    }
}

static inline size_t align_up(size_t v, size_t a) { return (v + a - 1) & ~(a - 1); }

extern "C" void kernel_launch(void* const* d_in, const int* in_sizes, int n_in,
                              void* d_out, int out_size, void* d_ws, size_t ws_size,
                              hipStream_t stream) {
    const float* x     = (const float*)d_in[0];
    const int*   ei    = (const int*)d_in[1];
    const int*   batch = (const int*)d_in[2];
    const int*   km    = (const int*)d_in[3];
    const int*   um    = (const int*)d_in[4];
    const int*   om    = (const int*)d_in[5];
    const float* mw    = (const float*)d_in[6];
    const float* emb_W = (const float*)d_in[7];
    const float* emb_b = (const float*)d_in[8];
    const float* gcn_W = (const float*)d_in[9];
    const float* gcn_b = (const float*)d_in[10];
    const float* fc1_W = (const float*)d_in[11];
    const float* fc1_b = (const float*)d_in[12];
    const float* out_W = (const float*)d_in[13];
    const float* out_b = (const float*)d_in[14];
    (void)om;

    const int n_nodes  = in_sizes[0] / 64;
    const int n_edges  = in_sizes[1] / 2;
    const int s0 = in_sizes[3], s1 = in_sizes[4];
    const int n_graphs = out_size;  // 256

    const int* row = ei;
    const int* col = ei + n_edges;

    const int NB  = (n_nodes + 63) >> 6;   // 1563 buckets of 64 nodes
    const int NGB = (NB + 15) / 16;        // kB2 blocks
    const int nused = (n_edges + CHK - 1) >> CHKSH;  // 733 used chunks

    // ---- workspace layout (~35 MB) ----
    char* base = (char*)d_ws;
    float*    pooled = (float*)base;    base += (size_t)n_graphs * 32 * 4;   // zeroed
    uint16_t* cnt    = (uint16_t*)base; base += (size_t)NCHUNK * NB * 2;     // 3.2 MB
    uint16_t* offTT  = (uint16_t*)base; base += (size_t)NCHUNK * NB * 2;     // 3.2 MB
    int*      tot    = (int*)base;      base += (size_t)NB * 4;
    int*      base_  = (int*)base;      base += (size_t)(NB + 1) * 4;
    float*    Wfull  = (float*)base;    base += 2048 * 4;
    float*    hWbias = (float*)base;    base += 32 * 4;
    int*      cnt2   = (int*)base;      base += (size_t)NCB * NCHUNK * 4;    // 1.57 MB
    int*      csrB   = (int*)base;      base += (size_t)n_edges * 4;         // 12 MB
    base = (char*)align_up((size_t)base, 64);
    // UNION region: kl (13.5 MB, live kA1..kC) overlaps hWs (6.4 MB, live
    // k4f..kD). kC finishes before k4f starts (stream order) -> safe.
    uint16_t* kl  = (uint16_t*)base;
    __half*   hWs = (__half*)base;
    base += (size_t)nused * NCB * CELLCAP * 2;                               // 13.5 MB

    hipMemsetAsync(pooled, 0, (size_t)n_graphs * 32 * 4, stream);

    kA1<<<NCHUNK + NCB, BLK, 0, stream>>>(col, cnt, n_edges, NB, km, um, s0, s1,
                                          kl, cnt2);
    kB2<<<NGB, BLK, 0, stream>>>(cnt, offTT, tot, NB);
    kBase3<<<9, BLK, 0, stream>>>(tot, base_, NB, emb_W, emb_b, gcn_W, Wfull, hWbias);
    kC_scatter<<<NCHUNK, BLK, 0, stream>>>(row, col, kl, cnt2, base_, offTT, csrB,
                                           n_edges, NB);
    k4f_gemm<<<NB, BLK, 0, stream>>>(x, Wfull, hWbias, base_, csrB, mw, hWs, n_nodes);
    kD_gather<<<NB, BLK, 0, stream>>>(base_, csrB, (const __half2*)hWs, mw,
                                      gcn_b, batch, pooled, n_nodes);
    k7_head<<<1, BLK, 0, stream>>>(pooled, fc1_W, fc1_b, out_W, out_b, (float*)d_out, n_graphs);
}

// Round 8
// 273.113 us; speedup vs baseline: 1.4615x; 1.0530x over previous
//
#include <hip/hip_runtime.h>
#include <hip/hip_fp16.h>
#include <stdint.h>

// GCN forward. N=100000, E=3000000, G=256, F_IN=64, NHID=32.
// R1: 96M global scatter-atomics = L2 atomic ceiling (312us) -> gather.
// R2: naive CSR build = 16x write amplification (random sub-line stores).
// R6: small hot global atomic arrays = 32B line ping-pong per op.
// R13: kC single pass, XCD-grouped chunk remap -> monotone per-bucket
//     sub-runs, clean writes, edges read once.
// R14 FAILED: atomicOr scatter = same ~32B/op sector cost + throttle.
// R15: default cls=2 via memset + scatter only km/um: 274.5us. BASELINE.
// R16 FAILED: XCD-pinning doesn't stop random sub-line store amplification.
// R17/R18/R19 (kl-cell detour): private 192B cells DO write clean
//     (WRITE 78->14MB) but kA1 dur UNCHANGED (~53-55us across byte-store,
//     trailing-kl, overlapped-kl variants) -> kA1's floor is histogram+
//     stream structure, NOT class-scatter bytes. kl net -13us vs R15
//     (kC clsL staging + cnt2 traffic). REVERTED per decision rule.
// R20 (this round): R15 base + kD SPLIT: 2 blocks/bucket (grid 3126,
//     12.2/CU), each owns 32 nodes; count/sort filtered by half; extra
//     csrB segment read is L2-hit (R17 evidence). LDS 21.5->15.7KB.
//     Predict kD 51->~36us, total ~259.

#define BLK 256
#define NCHUNK 512          // edge chunks for count/scatter
#define MAXNB 1600          // max buckets (N<=102400)
#define ENTCAP 2560         // per-half-bucket LDS entries (safe clamp)

// kA1: fused. Blocks [0,NCHUNK): per-chunk node-bucket histogram (LDS).
// Blocks [NCHUNK, NCHUNK+128): edge class from masks, plain byte stores
// (fire-and-forget). Only km (cls 0) and um (cls 1); ewc pre-memset to 2.
__global__ void kA1(const int* __restrict__ col, int* __restrict__ cnt,
                    int n_edges, int NB,
                    const int* __restrict__ km, const int* __restrict__ um,
                    int s0, int s1,
                    uint8_t* __restrict__ ewc) {
    int t = threadIdx.x;
    if (blockIdx.x < NCHUNK) {
        __shared__ int lh[MAXNB];
        int c = blockIdx.x;
        for (int b = t; b < NB; b += BLK) lh[b] = 0;
        __syncthreads();
        int chunk = (n_edges + NCHUNK - 1) / NCHUNK;
        int e0 = c * chunk, e1 = min(e0 + chunk, n_edges);
        for (int e = e0 + t; e < e1; e += BLK) atomicAdd(&lh[col[e] >> 6], 1);
        __syncthreads();
        for (int b = t; b < NB; b += BLK) cnt[(size_t)c * NB + b] = lh[b];
    } else {
        int gid = (blockIdx.x - NCHUNK) * BLK + t;
        int total = s0 + s1;
        for (int i = gid; i < total; i += 128 * BLK) {
            int e; uint8_t cls;
            if (i < s0) { e = km[i];      cls = 0; }
            else        { e = um[i - s0]; cls = 1; }
            ewc[e] = cls;
        }
    }
}

// kB2: 16 node-buckets per block. Tile cnt through LDS with coalesced 64B
// reads, scan over chunks, write offTT TRANSPOSED for sequential kC reads.
__global__ void kB2(const int* __restrict__ cnt, int* __restrict__ offTT,
                    int* __restrict__ tot, int NB) {
    __shared__ int tile[NCHUNK * 16];     // 32KB
    __shared__ int segs[16][17];
    int t = threadIdx.x;
    int b0 = blockIdx.x * 16;
    for (int idx = t; idx < NCHUNK * 16; idx += BLK) {
        int c = idx >> 4, b = idx & 15;
        tile[idx] = (b0 + b < NB) ? cnt[(size_t)c * NB + b0 + b] : 0;
    }
    __syncthreads();
    int b = t & 15, seg = t >> 4;         // 16 segs x 16 buckets
    int psum = 0;
#pragma unroll
    for (int k = 0; k < 32; ++k) psum += tile[(seg * 32 + k) * 16 + b];
    segs[seg][b] = psum;
    __syncthreads();
    int ex = 0;
    for (int ss = 0; ss < seg; ++ss) ex += segs[ss][b];
    int run = ex;
#pragma unroll
    for (int k = 0; k < 32; ++k) {
        int c = seg * 32 + k;
        if (b0 + b < NB) offTT[(size_t)c * NB + b0 + b] = run;
        run += tile[c * 16 + b];
    }
    if (seg == 15 && b0 + b < NB) tot[b0 + b] = run;
}

// kBase3: fused. Blocks 0..7: fold emb through gcn (Wfull, hWbias).
// Block 8: exclusive scan of tot[NB] -> base_[0..NB].
__global__ void kBase3(const int* __restrict__ tot, int* __restrict__ base_, int NB,
                       const float* __restrict__ emb_W, const float* __restrict__ emb_b,
                       const float* __restrict__ gcn_W,
                       float* __restrict__ Wfull, float* __restrict__ hWbias) {
    int t = threadIdx.x;
    if (blockIdx.x < 8) {
        int k = blockIdx.x * 8 + (t >> 5), j = t & 31;
        float acc;
        if (k == 0) {
            acc = gcn_W[j];
        } else {
            int m = k - 1;
            acc = 0.0f;
#pragma unroll 9
            for (int tt = 0; tt < 63; ++tt)
                acc += emb_W[m * 63 + tt] * gcn_W[(1 + tt) * 32 + j];
        }
        Wfull[k * 32 + j] = acc;
        if (blockIdx.x == 0 && t < 32) {
            float bacc = 0.0f;
            for (int tt = 0; tt < 63; ++tt)
                bacc += emb_b[tt] * gcn_W[(1 + tt) * 32 + t];
            hWbias[t] = bacc;
        }
    } else {
        __shared__ int s[BLK];
        const int K = 7;  // 256*7 = 1792 >= MAXNB
        int v[K]; int sum = 0;
#pragma unroll
        for (int k = 0; k < K; ++k) {
            int i = t * K + k;
            v[k] = (i < NB) ? tot[i] : 0;
            sum += v[k];
        }
        s[t] = sum; __syncthreads();
        for (int st = 1; st < BLK; st <<= 1) {
            int x = (t >= st) ? s[t - st] : 0;
            __syncthreads(); s[t] += x; __syncthreads();
        }
        int ex = (t == 0) ? 0 : s[t - 1];
#pragma unroll
        for (int k = 0; k < K; ++k) {
            int i = t * K + k;
            if (i < NB) base_[i] = ex;
            ex += v[k];
        }
        if (t == BLK - 1) base_[NB] = s[BLK - 1];
    }
}

// kC: SINGLE-PASS scatter with XCD-grouped chunk remap.
// chunk = (blockIdx&7)*(NCHUNK/8) + (blockIdx>>3): XCD k processes chunks
// [k*64,(k+1)*64) -> each bucket's csrB segment is written as 8 contiguous
// per-XCD sub-runs (monotone offsets in chunk). Edges read ONCE.
// Entry = (local_col<<19)|(row<<2)|cls.
__global__ void kC_scatter(const int* __restrict__ row, const int* __restrict__ col,
                           const uint8_t* __restrict__ ewc, const int* __restrict__ base_,
                           const int* __restrict__ offTT, int* __restrict__ csrB,
                           int n_edges, int NB) {
    __shared__ int cur[MAXNB];
    int t = threadIdx.x;
    int c = (blockIdx.x & 7) * (NCHUNK / 8) + (blockIdx.x >> 3);
    const int* offrow = offTT + (size_t)c * NB;
    for (int b = t; b < NB; b += BLK) cur[b] = base_[b] + offrow[b];
    __syncthreads();
    int chunk = (n_edges + NCHUNK - 1) / NCHUNK;
    int e0 = c * chunk, e1 = min(e0 + chunk, n_edges);
    for (int e = e0 + t; e < e1; e += BLK) {
        int cc = col[e];
        int pos = atomicAdd(&cur[cc >> 6], 1);
        csrB[pos] = ((cc & 63) << 19) | (row[e] << 2) | (ewc[e] & 3);
    }
}

// k4f: fused degree + GEMM per 64-node bucket.
__global__ void k4f_gemm(const float* __restrict__ x, const float* __restrict__ Wfull,
                         const float* __restrict__ hWbias, const int* __restrict__ base_,
                         const int* __restrict__ csrB, const float* __restrict__ mw,
                         __half* __restrict__ hWs, int n_nodes) {
    __shared__ float Wl[64 * 32];      // 8KB
    __shared__ float xs[64 * 64];      // 16KB
    __shared__ int ct4[256];           // 1KB
    __shared__ float dv[64];
    int b = blockIdx.x, t = threadIdx.x;
    for (int idx = t; idx < 2048; idx += BLK) Wl[idx] = Wfull[idx];
    if (t < 256) ct4[t] = 0;
    int rowBase = b * 64;
    for (int idx = t; idx < 4096; idx += BLK) {
        int r = rowBase + (idx >> 6);
        xs[idx] = (r < n_nodes) ? x[(size_t)r * 64 + (idx & 63)] : 0.0f;
    }
    __syncthreads();
    int p0 = base_[b], p1 = base_[b + 1];
    for (int p = p0 + t; p < p1; p += BLK) {
        int e = csrB[p];
        atomicAdd(&ct4[((e >> 19) << 2) | (e & 3)], 1);
    }
    __syncthreads();
    if (t < 64) {
        float a = mw[0], bb = mw[1], c3 = mw[2];
        float m = fmaxf(a, fmaxf(bb, c3));
        float ea = __expf(a - m), eb = __expf(bb - m), ec = __expf(c3 - m);
        float inv = 1.0f / (ea + eb + ec);
        float deg = (ea * inv) * (float)ct4[t * 4]
                  + (eb * inv) * (float)ct4[t * 4 + 1]
                  + (ec * inv) * (float)ct4[t * 4 + 2]
                  + (float)ct4[t * 4 + 3]
                  + 1.0f;
        dv[t] = rsqrtf(deg);
    }
    __syncthreads();
    int j = t & 31, lr = t >> 5;
#pragma unroll
    for (int k8 = 0; k8 < 8; ++k8) {
        int r = lr + 8 * k8;
        int n = rowBase + r;
        if (n < n_nodes) {
            float acc = hWbias[j];
#pragma unroll
            for (int k = 0; k < 64; ++k)
                acc += xs[r * 64 + k] * Wl[k * 32 + j];
            hWs[(size_t)n * 32 + j] = __float2half(dv[r] * acc);
        }
    }
}

// kD: SPLIT consumer — 2 blocks per bucket, each owns 32 nodes (half h).
// Count/sort passes filter by half (lc>>5 == h); extra csrB segment read
// is an L2 hit. Per-node register gather (16 lanes/node, half2, 8 in
// flight), relu, run-length pool.
__global__ void kD_gather(const int* __restrict__ base_, const int* __restrict__ csrB,
                          const __half2* __restrict__ hws2,
                          const float* __restrict__ mw, const float* __restrict__ gcn_b,
                          const int* __restrict__ batch, float* __restrict__ pooled,
                          int n_nodes) {
    __shared__ int ent[ENTCAP];
    __shared__ float res[32 * 33];
    __shared__ int ct4[128];
    __shared__ int ct[32], st[32], cur[32];
    __shared__ float dl[32], gb[32];
    __shared__ int bl[32];
    int b = blockIdx.x >> 1, h = blockIdx.x & 1, t = threadIdx.x;
    int nodeBase = b * 64 + h * 32;
    int hb = h << 5;
    if (t < 128) ct4[t] = 0;
    if (t < 32) {
        int n = nodeBase + t;
        bl[t] = (n < n_nodes) ? batch[n] : -1;
        gb[t] = gcn_b[t];
    }
    __syncthreads();
    int p0 = base_[b], p1 = base_[b + 1];
    int m = min(p1 - p0, ENTCAP);     // clamp (own-half count <= m <= ENTCAP)
    int p1c = p0 + m;
    for (int p = p0 + t; p < p1c; p += BLK) {
        int e = csrB[p];
        int lc = e >> 19;
        if ((lc & 32) == hb) atomicAdd(&ct4[((lc & 31) << 2) | (e & 3)], 1);
    }
    __syncthreads();
    float a = mw[0], bb = mw[1], c3 = mw[2];
    float mx = fmaxf(a, fmaxf(bb, c3));
    float ea = __expf(a - mx), eb = __expf(bb - mx), ec = __expf(c3 - mx);
    float inv = 1.0f / (ea + eb + ec);
    float w0 = ea * inv, w1 = eb * inv, w2 = ec * inv;
    if (t < 32) {
        int c0 = ct4[t * 4], c1 = ct4[t * 4 + 1], c2 = ct4[t * 4 + 2], c33 = ct4[t * 4 + 3];
        ct[t] = c0 + c1 + c2 + c33;
        dl[t] = rsqrtf(w0 * (float)c0 + w1 * (float)c1 + w2 * (float)c2
                       + (float)c33 + 1.0f);
    }
    __syncthreads();
    if (t < 32) st[t] = ct[t];
    __syncthreads();
    for (int off = 1; off < 32; off <<= 1) {
        int v = (t < 32 && t >= off) ? st[t - off] : 0;
        __syncthreads();
        if (t < 32) st[t] += v;
        __syncthreads();
    }
    if (t < 32) { st[t] -= ct[t]; cur[t] = st[t]; }
    __syncthreads();
    for (int p = p0 + t; p < p1c; p += BLK) {
        int e = csrB[p];
        int lc = e >> 19;
        if ((lc & 32) == hb) {
            int pos = atomicAdd(&cur[lc & 31], 1);
            ent[pos] = e;
        }
    }
    __syncthreads();
    int grp = t >> 4, j2 = t & 15;
#pragma unroll
    for (int idx = 0; idx < 2; ++idx) {
        int lc = grp + 16 * idx;          // 0..31 local
        int n = nodeBase + lc;
        float rx = 0.0f, ry = 0.0f;
        if (n < n_nodes) {
            int s = st[lc], end = s + ct[lc];
            float ax = 0.0f, ay = 0.0f;
            int p = s;
            for (; p + 8 <= end; p += 8) {
                int e0 = ent[p],     e1 = ent[p + 1], e2 = ent[p + 2], e3 = ent[p + 3];
                int e4 = ent[p + 4], e5 = ent[p + 5], e6 = ent[p + 6], e7 = ent[p + 7];
                __half2 h0 = hws2[(size_t)((e0 >> 2) & 0x1FFFF) * 16 + j2];
                __half2 h1 = hws2[(size_t)((e1 >> 2) & 0x1FFFF) * 16 + j2];
                __half2 h2 = hws2[(size_t)((e2 >> 2) & 0x1FFFF) * 16 + j2];
                __half2 h3 = hws2[(size_t)((e3 >> 2) & 0x1FFFF) * 16 + j2];
                __half2 h4 = hws2[(size_t)((e4 >> 2) & 0x1FFFF) * 16 + j2];
                __half2 h5 = hws2[(size_t)((e5 >> 2) & 0x1FFFF) * 16 + j2];
                __half2 h6 = hws2[(size_t)((e6 >> 2) & 0x1FFFF) * 16 + j2];
                __half2 h7 = hws2[(size_t)((e7 >> 2) & 0x1FFFF) * 16 + j2];
                float f0 = ((e0 & 3) == 0) ? w0 : (((e0 & 3) == 1) ? w1 : w2);
                float f1 = ((e1 & 3) == 0) ? w0 : (((e1 & 3) == 1) ? w1 : w2);
                float f2 = ((e2 & 3) == 0) ? w0 : (((e2 & 3) == 1) ? w1 : w2);
                float f3 = ((e3 & 3) == 0) ? w0 : (((e3 & 3) == 1) ? w1 : w2);
                float f4 = ((e4 & 3) == 0) ? w0 : (((e4 & 3) == 1) ? w1 : w2);
                float f5 = ((e5 & 3) == 0) ? w0 : (((e5 & 3) == 1) ? w1 : w2);
                float f6 = ((e6 & 3) == 0) ? w0 : (((e6 & 3) == 1) ? w1 : w2);
                float f7 = ((e7 & 3) == 0) ? w0 : (((e7 & 3) == 1) ? w1 : w2);
                float2 g0 = __half22float2(h0), g1 = __half22float2(h1);
                float2 g2 = __half22float2(h2), g3 = __half22float2(h3);
                float2 g4 = __half22float2(h4), g5 = __half22float2(h5);
                float2 g6 = __half22float2(h6), g7 = __half22float2(h7);
                ax += f0 * g0.x + f1 * g1.x + f2 * g2.x + f3 * g3.x
                    + f4 * g4.x + f5 * g5.x + f6 * g6.x + f7 * g7.x;
                ay += f0 * g0.y + f1 * g1.y + f2 * g2.y + f3 * g3.y
                    + f4 * g4.y + f5 * g5.y + f6 * g6.y + f7 * g7.y;
            }
            for (; p < end; ++p) {
                int e0 = ent[p];
                __half2 h0 = hws2[(size_t)((e0 >> 2) & 0x1FFFF) * 16 + j2];
                float f0 = ((e0 & 3) == 0) ? w0 : (((e0 & 3) == 1) ? w1 : w2);
                float2 g0 = __half22float2(h0);
                ax += f0 * g0.x; ay += f0 * g0.y;
            }
            float2 self = __half22float2(hws2[(size_t)n * 16 + j2]);
            float di = dl[lc];
            rx = fmaxf(di * (ax + self.x) + gb[2 * j2], 0.0f);
            ry = fmaxf(di * (ay + self.y) + gb[2 * j2 + 1], 0.0f);
        }
        res[lc * 33 + 2 * j2]     = rx;
        res[lc * 33 + 2 * j2 + 1] = ry;
    }
    __syncthreads();
    if (t < 32) {
        int j = t;
        float sum = 0.0f; int g0 = bl[0];
        for (int lc = 0; lc < 32; ++lc) {
            if (bl[lc] < 0) break;
            float val = res[lc * 33 + j];
            if (bl[lc] != g0) { atomicAdd(&pooled[g0 * 32 + j], sum); sum = 0.0f; g0 = bl[lc]; }
            sum += val;
        }
        if (g0 >= 0) atomicAdd(&pooled[g0 * 32 + j], sum);
    }
}

// k7: head: z = relu(pooled @ fc1_W + fc1_b); out = z @ out_W + out_b
__global__ void k7_head(const float* __restrict__ pooled, const float* __restrict__ fc1_W,
                        const float* __restrict__ fc1_b, const float* __restrict__ out_W,
                        const float* __restrict__ out_b, float* __restrict__ out,
                        int n_graphs) {
    __shared__ float Wl[32 * 32];
    __shared__ float bl[32];
    __shared__ float owl[32];
    int t = threadIdx.x;
    for (int idx = t; idx < 1024; idx += BLK) Wl[idx] = fc1_W[idx];
    if (t < 32) { bl[t] = fc1_b[t]; owl[t] = out_W[t]; }
    __syncthreads();
    if (t < n_graphs) {
        float p[32];
#pragma unroll
        for (int k = 0; k < 32; ++k) p[k] = pooled[t * 32 + k];
        float acc = 0.0f;
        for (int j = 0; j < 32; ++j) {
            float z = bl[j];
#pragma unroll
            for (int k = 0; k < 32; ++k) z += p[k] * Wl[k * 32 + j];
            z = fmaxf(z, 0.0f);
            acc += z * owl[j];
        }
        out[t] = acc + out_b[0];
    }
}

static inline size_t align_up(size_t v, size_t a) { return (v + a - 1) & ~(a - 1); }

extern "C" void kernel_launch(void* const* d_in, const int* in_sizes, int n_in,
                              void* d_out, int out_size, void* d_ws, size_t ws_size,
                              hipStream_t stream) {
    const float* x     = (const float*)d_in[0];
    const int*   ei    = (const int*)d_in[1];
    const int*   batch = (const int*)d_in[2];
    const int*   km    = (const int*)d_in[3];
    const int*   um    = (const int*)d_in[4];
    const int*   om    = (const int*)d_in[5];
    const float* mw    = (const float*)d_in[6];
    const float* emb_W = (const float*)d_in[7];
    const float* emb_b = (const float*)d_in[8];
    const float* gcn_W = (const float*)d_in[9];
    const float* gcn_b = (const float*)d_in[10];
    const float* fc1_W = (const float*)d_in[11];
    const float* fc1_b = (const float*)d_in[12];
    const float* out_W = (const float*)d_in[13];
    const float* out_b = (const float*)d_in[14];
    (void)om;

    const int n_nodes  = in_sizes[0] / 64;
    const int n_edges  = in_sizes[1] / 2;
    const int s0 = in_sizes[3], s1 = in_sizes[4];
    const int n_graphs = out_size;  // 256

    const int* row = ei;
    const int* col = ei + n_edges;

    const int NB  = (n_nodes + 63) >> 6;   // 1563 buckets of 64 nodes
    const int NGB = (NB + 15) / 16;        // kB2 blocks

    // ---- workspace layout (~28.3 MB) ----
    char* base = (char*)d_ws;
    float*   pooled = (float*)base;   base += (size_t)n_graphs * 32 * 4;   // zeroed
    int*     cnt    = (int*)base;     base += (size_t)NCHUNK * NB * 4;     // 3.2 MB
    int*     offTT  = (int*)base;     base += (size_t)NCHUNK * NB * 4;     // 3.2 MB
    int*     tot    = (int*)base;     base += (size_t)NB * 4;
    int*     base_  = (int*)base;     base += (size_t)(NB + 1) * 4;
    float*   Wfull  = (float*)base;   base += 2048 * 4;
    float*   hWbias = (float*)base;   base += 32 * 4;
    uint8_t* ewc    = (uint8_t*)base; base += align_up((size_t)n_edges, 64);
    int*     csrB   = (int*)base;     base += (size_t)n_edges * 4;         // 12 MB
    base = (char*)align_up((size_t)base, 64);
    __half*  hWs    = (__half*)base;  base += (size_t)n_nodes * 32 * 2;    // 6.4 MB

    hipMemsetAsync(pooled, 0, (size_t)n_graphs * 32 * 4, stream);
    hipMemsetAsync(ewc, 2, align_up((size_t)n_edges, 64), stream);  // default cls=2 (obs)

    kA1<<<NCHUNK + 128, BLK, 0, stream>>>(col, cnt, n_edges, NB,
                                          km, um, s0, s1, ewc);
    kB2<<<NGB, BLK, 0, stream>>>(cnt, offTT, tot, NB);
    kBase3<<<9, BLK, 0, stream>>>(tot, base_, NB, emb_W, emb_b, gcn_W, Wfull, hWbias);
    kC_scatter<<<NCHUNK, BLK, 0, stream>>>(row, col, ewc, base_, offTT, csrB,
                                           n_edges, NB);
    k4f_gemm<<<NB, BLK, 0, stream>>>(x, Wfull, hWbias, base_, csrB, mw, hWs, n_nodes);
    kD_gather<<<2 * NB, BLK, 0, stream>>>(base_, csrB, (const __half2*)hWs, mw,
                                          gcn_b, batch, pooled, n_nodes);
    k7_head<<<1, BLK, 0, stream>>>(pooled, fc1_W, fc1_b, out_W, out_b, (float*)d_out, n_graphs);
}